// Round 4
// baseline (311.543 us; speedup 1.0000x reference)
//
#include <hip/hip_runtime.h>
#include <hip/hip_bf16.h>
#include <math.h>

#define B_ 2
#define T_ 2048
#define C_ 2048
#define H_ 16
#define KVH_ 4
#define HD_ 128
#define G_ (H_ / KVH_)
#define MROWS (B_ * T_)                    // 4096
#define NQKV (H_ * HD_ + 2 * KVH_ * HD_)   // 3072
#define KOFF (H_ * HD_)                    // 2048
#define VOFF (H_ * HD_ + KVH_ * HD_)       // 2560
#define L2T (13.287712379549449f / 64.0f)  // log2(10000)/64

typedef __hip_bfloat16 bf16;
typedef short bf16x8 __attribute__((ext_vector_type(8)));   // 8 bf16 = 4 VGPR
typedef short bf16x4 __attribute__((ext_vector_type(4)));   // 4 bf16 = 2 VGPR
typedef float f32x4 __attribute__((ext_vector_type(4)));

__device__ __forceinline__ void gload_lds16(const void* g, void* l) {
  __builtin_amdgcn_global_load_lds(
      (const __attribute__((address_space(1))) unsigned int*)g,
      (__attribute__((address_space(3))) unsigned int*)l, 16, 0, 0);
}

static __device__ __forceinline__ f32x4 mfma32k(bf16x8 a, bf16x8 b, f32x4 c) {
  return __builtin_amdgcn_mfma_f32_16x16x32_bf16(a, b, c, 0, 0, 0);
}

// fast RNE f32->bf16 (no NaN handling; inputs are finite)
static __device__ __forceinline__ short f2bf(float x) {
  unsigned u = __builtin_bit_cast(unsigned, x);
  u += 0x7FFFu + ((u >> 16) & 1u);
  return (short)(u >> 16);
}

// bf16 (raw short) -> f32
static __device__ __forceinline__ float bfh2f(short h) {
  unsigned u = ((unsigned)(unsigned short)h) << 16;
  return __builtin_bit_cast(float, u);
}

static __device__ __forceinline__ float fexp2(float x) {
#if __has_builtin(__builtin_amdgcn_exp2f)
  return __builtin_amdgcn_exp2f(x);
#else
  return exp2f(x);
#endif
}

// ---------------------------------------------------------------------------
// Fused prep: [0,8192)   cast x fp32->bf16
//             [8192,14336)  wq|wk|wv transpose-cast -> wqkvT [3072][2048]
//             [14336,18432) wo transpose-cast -> woT [2048][2048]
//             [18432,18944) RoPE cos/sin table [2048][64] float2
// ---------------------------------------------------------------------------
__global__ __launch_bounds__(256) void prep_kernel(
    const float* __restrict__ x, bf16* __restrict__ xb,
    const float* __restrict__ wq, const float* __restrict__ wk,
    const float* __restrict__ wv, bf16* __restrict__ wqkvT,
    const float* __restrict__ wo, bf16* __restrict__ woT,
    float2* __restrict__ tab) {
  __shared__ float t[32][33];
  int bid = blockIdx.x;
  if (bid < 8192) {                        // ---- cast x
    const int i = (bid * 256 + threadIdx.x) * 4;
    float4 v = *(const float4*)(x + i);
    xb[i + 0] = __float2bfloat16(v.x);
    xb[i + 1] = __float2bfloat16(v.y);
    xb[i + 2] = __float2bfloat16(v.z);
    xb[i + 3] = __float2bfloat16(v.w);
    return;
  }
  bid -= 8192;
  if (bid < 6144) {                        // ---- qkv weight transpose
    const int tx = threadIdx.x & 31, ty = threadIdx.x >> 5;
    const int c0 = (bid % 96) * 32;        // fused n-dim 0..3071
    const int r0 = (bid / 96) * 32;        // k-dim
    const float* src;
    int nn, ld;
    if (c0 < KOFF)      { src = wq; nn = c0;        ld = 2048; }
    else if (c0 < VOFF) { src = wk; nn = c0 - KOFF; ld = 512; }
    else                { src = wv; nn = c0 - VOFF; ld = 512; }
#pragma unroll
    for (int it = 0; it < 4; ++it)
      t[ty + 8 * it][tx] = src[(size_t)(r0 + ty + 8 * it) * ld + nn + tx];
    __syncthreads();
#pragma unroll
    for (int it = 0; it < 4; ++it)
      wqkvT[(size_t)(c0 + ty + 8 * it) * 2048 + r0 + tx] =
          __float2bfloat16(t[tx][ty + 8 * it]);
    return;
  }
  bid -= 6144;
  if (bid < 4096) {                        // ---- wo transpose
    const int tx = threadIdx.x & 31, ty = threadIdx.x >> 5;
    const int c0 = (bid & 63) * 32;
    const int r0 = (bid >> 6) * 32;
#pragma unroll
    for (int it = 0; it < 4; ++it)
      t[ty + 8 * it][tx] = wo[(size_t)(r0 + ty + 8 * it) * 2048 + c0 + tx];
    __syncthreads();
#pragma unroll
    for (int it = 0; it < 4; ++it)
      woT[(size_t)(c0 + ty + 8 * it) * 2048 + r0 + tx] =
          __float2bfloat16(t[tx][ty + 8 * it]);
    return;
  }
  bid -= 4096;
  {                                        // ---- RoPE table
    const int idx = bid * 256 + threadIdx.x;   // [0, 131072)
    const int tt = idx >> 6, i = idx & 63;
    const float invf = fexp2(-(float)i * L2T);
    float s, c;
    __sincosf((float)tt * invf, &s, &c);
    tab[idx] = make_float2(c, s);
  }
}

// ---------------------------------------------------------------------------
// Fused pack (PV-mfma32 layout, r4):
// K chunk ((bk*64 + tile)*8 + kt*4 + c)*512 + L*8 holds (RoPE'd)
//   K[b, t = tile*32 + ((L>>2)&3)*8 + kt*4 + (L&3), kvh][c*32 + (L>>4)*8 ..+8]
//   => QK output sA[kt] row m=quad*4+i corresponds to key quad*8 + kt*4 + i.
// V chunk ((bk*64 + tile)*8 + ht)*512 + L*8 holds
//   V[b, t = tile*32 + (L>>4)*8 + j, kvh][ht*16 + (L&15)]  (j = 0..7)
//   => exact A-operand of mfma_16x16x32 for PV (k = quad*8 + j).
// ---------------------------------------------------------------------------
__global__ __launch_bounds__(256) void pack_kv(const bf16* __restrict__ qkv,
                                               bf16* __restrict__ kp,
                                               bf16* __restrict__ vp,
                                               const float2* __restrict__ tab) {
  const int pid = blockIdx.x;
  if (pid < 512) {                         // ---- K with RoPE
    const int tile = pid & 63;
    const int bk = pid >> 6;               // b*KVH + kvh
    const int b = bk >> 2, kvh = bk & 3;
#pragma unroll
    for (int u = 0; u < 2; ++u) {
      const int t = threadIdx.x + u * 256; // chunk id 0..511
      const int kc = t >> 6, L = t & 63;
      const int trow = tile * 32 + ((L >> 2) & 3) * 8 + (kc >> 2) * 4 + (L & 3);
      const bf16* src = qkv + (size_t)(b * T_ + trow) * NQKV +
                        KOFF + kvh * HD_ + (kc & 3) * 32 + (L >> 4) * 8;
      bf16x8 vs = *(const bf16x8*)src;
      bf16x8 vpair = *(const bf16x8*)(src + (((kc & 2) == 0) ? 64 : -64));
      const float2* tp = tab + trow * 64 + (kc & 1) * 32 + (L >> 4) * 8;
      bf16x8 outv;
#pragma unroll
      for (int jj = 0; jj < 8; ++jj) {
        const float2 cs = tp[jj];
        const float a = bfh2f(vs[jj]), p = bfh2f(vpair[jj]);
        outv[jj] = f2bf(((kc & 2) == 0) ? (a * cs.x - p * cs.y)
                                        : (a * cs.x + p * cs.y));
      }
      *(bf16x8*)(kp + ((size_t)(bk * 64 + tile) * 8 + kc) * 512 + L * 8) = outv;
    }
    return;
  }
  {                                        // ---- V pack (no rope)
    const int pid2 = pid - 512;
    const int tile = pid2 & 63;
    const int bk = pid2 >> 6;
    const int b = bk >> 2, kvh = bk & 3;
#pragma unroll
    for (int u = 0; u < 2; ++u) {
      const int t = threadIdx.x + u * 256;
      const int ht = t >> 6, L = t & 63;
      const int colL = L & 15, quad = L >> 4;
      const bf16* base = qkv + (size_t)(b * T_ + tile * 32 + quad * 8) * NQKV +
                         VOFF + kvh * HD_ + ht * 16 + colL;
      bf16x8 v;
#pragma unroll
      for (int jj = 0; jj < 8; ++jj)
        v[jj] = *(const short*)(base + (size_t)jj * NQKV);
      *(bf16x8*)(vp + ((size_t)(bk * 64 + tile) * 8 + ht) * 512 + L * 8) = v;
    }
  }
}

// ---------------------------------------------------------------------------
// bf16 MFMA GEMM (m97 structure, kept for out-proj): C = A @ Bt^T
// ---------------------------------------------------------------------------
template <bool BF16OUT>
__global__ __launch_bounds__(256, 2) void gemm_mfma(
    const bf16* __restrict__ A, const bf16* __restrict__ Bt, void* __restrict__ Cout,
    const float* __restrict__ bq, const float* __restrict__ bk2,
    const float* __restrict__ bv2, int M, int N, int K) {
  __shared__ __align__(16) bf16 As[128 * 32];
  __shared__ __align__(16) bf16 Bs[128 * 32];
  const int tid = threadIdx.x;
  const int w = tid >> 6, lane = tid & 63;
  const int colL = lane & 15, quad = lane >> 4;
  const int wm = w & 1, wn = w >> 1;
  const int r0 = blockIdx.y * 128, c0 = blockIdx.x * 128;

  f32x4 acc[4][4];
  const f32x4 zero = {0.f, 0.f, 0.f, 0.f};
#pragma unroll
  for (int mt = 0; mt < 4; ++mt)
#pragma unroll
    for (int nt = 0; nt < 4; ++nt) acc[mt][nt] = zero;

  for (int k0 = 0; k0 < K; k0 += 32) {
    __syncthreads();
#pragma unroll
    for (int it = 0; it < 2; ++it) {
      const int seg = it * 4 + w;
      const int idx = seg * 64 + lane;
      const int row = idx >> 2, off = idx & 3;
      gload_lds16(A + (size_t)(r0 + row) * K + k0 + off * 8, &As[seg * 512]);
      gload_lds16(Bt + (size_t)(c0 + row) * K + k0 + off * 8, &Bs[seg * 512]);
    }
    __syncthreads();
    bf16x8 af[4], bfv[4];
#pragma unroll
    for (int mt = 0; mt < 4; ++mt)
      af[mt] = *(const bf16x8*)&As[(wm * 64 + mt * 16 + colL) * 32 + quad * 8];
#pragma unroll
    for (int nt = 0; nt < 4; ++nt)
      bfv[nt] = *(const bf16x8*)&Bs[(wn * 64 + nt * 16 + colL) * 32 + quad * 8];
#pragma unroll
    for (int mt = 0; mt < 4; ++mt)
#pragma unroll
      for (int nt = 0; nt < 4; ++nt)
        acc[mt][nt] =
            __builtin_amdgcn_mfma_f32_16x16x32_bf16(af[mt], bfv[nt], acc[mt][nt], 0, 0, 0);
  }

#pragma unroll
  for (int nt = 0; nt < 4; ++nt) {
    const int c = c0 + wn * 64 + nt * 16 + colL;
    float bias = 0.f;
    if (bq) bias = (c < KOFF) ? bq[c] : (c < VOFF ? bk2[c - KOFF] : bv2[c - VOFF]);
#pragma unroll
    for (int mt = 0; mt < 4; ++mt) {
#pragma unroll
      for (int i = 0; i < 4; ++i) {
        const int r = r0 + wm * 64 + mt * 16 + quad * 4 + i;
        const float v = acc[mt][nt][i] + bias;
        if (BF16OUT)
          ((bf16*)Cout)[(size_t)r * N + c] = __float2bfloat16(v);
        else
          ((float*)Cout)[(size_t)r * N + c] = v;
      }
    }
  }
}

// ---------------------------------------------------------------------------
// 8-phase 256x256xBK=64 MFMA GEMM for the QKV projection (T2+T3+T4+T5).
// 512 thr = 8 waves (2M x 4N); per-wave C = 128 x 64; acc[8][4]; LDS 128KB
// (2 bufs x [256 rows][64 k] x A,B). 4 phases per K-tile: (mh,ks) in
// {(0,0),(1,0),(0,1),(1,1)}, 16 MFMA each, setprio-wrapped, 2 barriers/phase.
// T2 swizzle (BK=64 -> 8 x 16B slots/row): read slot' = (ks*4+quad)^(row&7);
// write side stays LINEAR for global_load_lds, with the SAME involution
// pre-applied to the global source k-slot ((L&7)^(L>>3); each gload covers an
// 8-row-aligned group so row&7 == L>>3). Quad-granular prefetch of tile t+1
// spread over phases: p1 issues Aq0,Aq2; p2 Bq0,Bq1; p3 Bq2,Bq3; p4 Aq1,Aq3.
// Counted waits (per-wave FIFO ledger): vmcnt(2) at p1-end (guards Aq1,Aq3(t)
// for p2; leaves Aq0,Aq2(t+1) in flight) and vmcnt(2) at p4-end (guards
// Aq0,Aq2,B*(t+1) for next p1; leaves Aq1,Aq3(t+1)). Never 0 in steady state.
// Buf parity: reads hit buf (t&1), stages write buf (t&1)^1 -> no WAR hazard.
// ---------------------------------------------------------------------------
__global__ __launch_bounds__(512, 1) void gemm_qkv8(
    const bf16* __restrict__ A, const bf16* __restrict__ Bt, bf16* __restrict__ Cout,
    const float* __restrict__ bq, const float* __restrict__ bk2,
    const float* __restrict__ bv2, int M, int N, int K) {
  __shared__ __align__(16) bf16 As[2][256 * 64];   // 64KB
  __shared__ __align__(16) bf16 Bs[2][256 * 64];   // 64KB
  const int tid = threadIdx.x;
  const int w = tid >> 6, lane = tid & 63;
  const int colL = lane & 15, quad = lane >> 4;
  const int wm = w >> 2, wn = w & 3;
  const int r0 = blockIdx.y * 256, c0 = blockIdx.x * 256;
  const int c7 = colL & 7;
  const int sl0 = (quad ^ c7) * 8;            // swizzled 16B-slot (elem), ks=0
  const int sl1 = ((quad + 4) ^ c7) * 8;      // ks=1
  const int lrow = lane >> 3;                 // src row within 8-row group
  const int lsl = ((lane & 7) ^ lrow) * 8;    // pre-swizzled src k-elems
  const int nk = K >> 6;

  const bf16* pa = A + (size_t)(r0 + w * 8 + lrow) * K + lsl;
  const bf16* pb = Bt + (size_t)(c0 + w * 8 + lrow) * K + lsl;

  auto stA = [&](int kt, int bi, int q) {   // stage 64-row quarter q of A
    gload_lds16(pa + (size_t)q * 64 * K + kt * 64, &As[bi][(q * 64 + w * 8) * 64]);
  };
  auto stB = [&](int kt, int bi, int q) {
    gload_lds16(pb + (size_t)q * 64 * K + kt * 64, &Bs[bi][(q * 64 + w * 8) * 64]);
  };

  f32x4 acc[8][4];
  const f32x4 zero = {0.f, 0.f, 0.f, 0.f};
#pragma unroll
  for (int m = 0; m < 8; ++m)
#pragma unroll
    for (int n = 0; n < 4; ++n) acc[m][n] = zero;

  // prologue: tile 0 in ledger order [Aq0,Aq2,B0,B1,B2,B3,Aq1,Aq3]
  stA(0, 0, 0); stA(0, 0, 2);
  stB(0, 0, 0); stB(0, 0, 1); stB(0, 0, 2); stB(0, 0, 3);
  stA(0, 0, 1); stA(0, 0, 3);
  asm volatile("s_waitcnt vmcnt(2)" ::: "memory");
  __builtin_amdgcn_s_barrier();

#pragma unroll 1
  for (int t = 0; t < nk; ++t) {
    const int bi = t & 1, nb = bi ^ 1;
    const bool st = (t + 1 < nk);
    const bf16* Ab = &As[bi][(wm * 128 + colL) * 64];
    const bf16* Bb = &Bs[bi][(wn * 64 + colL) * 64];
    bf16x8 afr[4], bfr[4];

    // ---- p1: (mh0, ks0) + B(ks0); stage Aq0,Aq2(t+1); vmcnt(2) at end
#pragma unroll
    for (int m = 0; m < 4; ++m) afr[m] = *(const bf16x8*)(Ab + m * 16 * 64 + sl0);
#pragma unroll
    for (int n = 0; n < 4; ++n) bfr[n] = *(const bf16x8*)(Bb + n * 16 * 64 + sl0);
    if (st) { stA(t + 1, nb, 0); stA(t + 1, nb, 2); }
    __builtin_amdgcn_s_barrier();
    __builtin_amdgcn_s_setprio(1);
#pragma unroll
    for (int m = 0; m < 4; ++m)
#pragma unroll
      for (int n = 0; n < 4; ++n) acc[m][n] = mfma32k(afr[m], bfr[n], acc[m][n]);
    __builtin_amdgcn_s_setprio(0);
    if (st) asm volatile("s_waitcnt vmcnt(2)" ::: "memory");
    else    asm volatile("s_waitcnt vmcnt(0)" ::: "memory");
    __builtin_amdgcn_s_barrier();

    // ---- p2: (mh1, ks0); stage Bq0,Bq1(t+1)
#pragma unroll
    for (int m = 0; m < 4; ++m)
      afr[m] = *(const bf16x8*)(Ab + (64 + m * 16) * 64 + sl0);
    if (st) { stB(t + 1, nb, 0); stB(t + 1, nb, 1); }
    __builtin_amdgcn_s_barrier();
    __builtin_amdgcn_s_setprio(1);
#pragma unroll
    for (int m = 0; m < 4; ++m)
#pragma unroll
      for (int n = 0; n < 4; ++n) acc[m + 4][n] = mfma32k(afr[m], bfr[n], acc[m + 4][n]);
    __builtin_amdgcn_s_setprio(0);
    __builtin_amdgcn_s_barrier();

    // ---- p3: (mh0, ks1) + B(ks1); stage Bq2,Bq3(t+1)
#pragma unroll
    for (int m = 0; m < 4; ++m) afr[m] = *(const bf16x8*)(Ab + m * 16 * 64 + sl1);
#pragma unroll
    for (int n = 0; n < 4; ++n) bfr[n] = *(const bf16x8*)(Bb + n * 16 * 64 + sl1);
    if (st) { stB(t + 1, nb, 2); stB(t + 1, nb, 3); }
    __builtin_amdgcn_s_barrier();
    __builtin_amdgcn_s_setprio(1);
#pragma unroll
    for (int m = 0; m < 4; ++m)
#pragma unroll
      for (int n = 0; n < 4; ++n) acc[m][n] = mfma32k(afr[m], bfr[n], acc[m][n]);
    __builtin_amdgcn_s_setprio(0);
    __builtin_amdgcn_s_barrier();

    // ---- p4: (mh1, ks1); stage Aq1,Aq3(t+1); vmcnt(2) at end
#pragma unroll
    for (int m = 0; m < 4; ++m)
      afr[m] = *(const bf16x8*)(Ab + (64 + m * 16) * 64 + sl1);
    if (st) { stA(t + 1, nb, 1); stA(t + 1, nb, 3); }
    __builtin_amdgcn_s_barrier();
    __builtin_amdgcn_s_setprio(1);
#pragma unroll
    for (int m = 0; m < 4; ++m)
#pragma unroll
      for (int n = 0; n < 4; ++n) acc[m + 4][n] = mfma32k(afr[m], bfr[n], acc[m + 4][n]);
    __builtin_amdgcn_s_setprio(0);
    if (st) asm volatile("s_waitcnt vmcnt(2)" ::: "memory");
    __builtin_amdgcn_s_barrier();
  }

  // epilogue: bias + bf16 store
#pragma unroll
  for (int nt = 0; nt < 4; ++nt) {
    const int c = c0 + wn * 64 + nt * 16 + colL;
    const float bias = (c < KOFF) ? bq[c] : (c < VOFF ? bk2[c - KOFF] : bv2[c - VOFF]);
#pragma unroll
    for (int mt = 0; mt < 8; ++mt) {
#pragma unroll
      for (int i = 0; i < 4; ++i) {
        const int r = r0 + wm * 128 + mt * 16 + quad * 4 + i;
        Cout[(size_t)r * N + c] = __float2bfloat16(acc[mt][nt][i] + bias);
      }
    }
  }
}

// ---------------------------------------------------------------------------
// Causal GQA flash attention v11: v10 + PV as single mfma_16x16x32 per ht.
// Key->MFMA-row permutation (pack_kv r4) makes lane quad hold keys quad*8..+7
// so concat(pf[0],pf[1]) is the exact B-operand and the repacked V fragment
// the exact A-operand of one K=32 MFMA (halves PV MFMA issue count).
// ---------------------------------------------------------------------------
#define FA_SCL2 (0.08838834764831845f * 1.4426950408889634f)  // scale * log2(e)
#define FA_M2 16.0f                                           // fixed max (exp2 domain)

__global__ __launch_bounds__(256, 3) void flash_mfma8(
    const bf16* __restrict__ qkv, const bf16* __restrict__ kp,
    const bf16* __restrict__ vp, bf16* __restrict__ ao,
    const float2* __restrict__ tab) {
  __shared__ __align__(16) bf16 KS[3][4096];   // 3 x 8KB
  __shared__ __align__(16) bf16 VS[3][4096];   // 3 x 8KB

  const int id = blockIdx.x;
  const int bk = id & 7;                   // b*KVH + kvh  (== XCD id under %8 rr)
  const int u = id >> 3;                   // 0..127
  const int jq = 127 - u;                  // descending work order (LPT)
  const int b = bk >> 2, kvh = bk & 3;
  const int w = threadIdx.x >> 6;          // wave = q-head within group
  const int h = (kvh << 2) | w;
  const int lane = threadIdx.x & 63;
  const int colL = lane & 15, quad = lane >> 4;
  const int myq0 = jq * 16;                // 16 q-rows per block
  const int nkv = (jq >> 1) + 1;           // 32-row kv tiles covering causal range

  const bf16* kpt = kp + ((size_t)(bk * 64)) * 4096 + (w * 2) * 512 + lane * 8;
  const bf16* vpt = vp + ((size_t)(bk * 64)) * 4096 + (w * 2) * 512 + lane * 8;

  auto stageK = [&](int tile, int slot) {
    const bf16* s = kpt + (size_t)tile * 4096;
    bf16* d = &KS[slot][(w * 2) * 512];    // wave-uniform base; HW adds lane*16B
    gload_lds16(s, d);
    gload_lds16(s + 512, d + 512);
  };
  auto stageV = [&](int tile, int slot) {
    const bf16* s = vpt + (size_t)tile * 4096;
    bf16* d = &VS[slot][(w * 2) * 512];
    gload_lds16(s, d);
    gload_lds16(s + 512, d + 512);
  };

  // Q fragments (B-operand of K·Q^T), RoPE'd in registers.
  bf16x8 qf[4];
  {
    const bf16* qg = qkv + (size_t)(b * T_ + myq0) * NQKV + h * HD_;
    bf16x8 rq[4];
#pragma unroll
    for (int c = 0; c < 4; ++c)
      rq[c] = *(const bf16x8*)(qg + (size_t)colL * NQKV + c * 32 + quad * 8);
    const float2* tp = tab + (myq0 + colL) * 64 + quad * 8;
    float2 cs0[8], cs1[8];
#pragma unroll
    for (int jj = 0; jj < 8; ++jj) { cs0[jj] = tp[jj]; cs1[jj] = tp[32 + jj]; }
#pragma unroll
    for (int c = 0; c < 4; ++c) {
#pragma unroll
      for (int jj = 0; jj < 8; ++jj) {
        const float2 cs = (c & 1) ? cs1[jj] : cs0[jj];
        const float a = bfh2f(rq[c][jj]), p = bfh2f(rq[c ^ 2][jj]);
        qf[c][jj] = f2bf((c & 2) ? (a * cs.x + p * cs.y)
                                 : (a * cs.x - p * cs.y));
      }
    }
  }

  const f32x4 zero = {0.f, 0.f, 0.f, 0.f};
  auto qk = [&](const bf16* Kb, f32x4 (&s_)[2]) {
    s_[0] = zero; s_[1] = zero;
#pragma unroll
    for (int c = 0; c < 4; ++c) {
      bf16x8 kf0 = *(const bf16x8*)(Kb + c * 512 + lane * 8);
      bf16x8 kf1 = *(const bf16x8*)(Kb + (4 + c) * 512 + lane * 8);
      s_[0] = mfma32k(kf0, qf[c], s_[0]);
      s_[1] = mfma32k(kf1, qf[c], s_[1]);
    }
  };

  f32x4 o[8];
#pragma unroll
  for (int ht = 0; ht < 8; ++ht) o[ht] = zero;
  float l_ = 0.f;

  // prologue: K tiles 0..2, V tiles 0..1; full drain; QK(0)
  stageK(0, 0);
  if (nkv > 1) stageK(1, 1);
  if (nkv > 2) stageK(2, 2);
  stageV(0, 0);
  if (nkv > 1) stageV(1, 1);
  asm volatile("s_waitcnt vmcnt(0)\n\ts_barrier" ::: "memory");

  f32x4 sA[2], sB[2];
  qk(KS[0], sA);

  int kStage = 0, kNext = 1, vRead = 0, vStage = 2;
#pragma unroll 1
  for (int tt = 0; tt < nkv; ++tt) {
    const bool sk = (tt + 3 < nkv), sv = (tt + 2 < nkv);
    if (sk) stageK(tt + 3, kStage);        // overwrites K(tt) slot: dead since iter tt-1
    if (sv) stageV(tt + 2, vStage);        // overwrites V(tt-1) slot: dead

    // QK(t+1) first: MFMA pipe busy while VALU does softmax(t)
    if (tt + 1 < nkv) qk(KS[kNext], sB);

    // softmax on sA (tile tt); key-in-frame = quad*8 + kt*4 + i (r4 mapping)
    bf16x4 pf[2];
    if (tt == nkv - 1) {
      const int qg = ((jq & 1) << 4) | colL;   // q offset within 32-row kv frame
#pragma unroll
      for (int kt = 0; kt < 2; ++kt) {
        const int kb = quad * 8 + kt * 4;
        float pv[4];
#pragma unroll
        for (int i = 0; i < 4; ++i) {
          float e = fexp2(fmaf(sA[kt][i], FA_SCL2, -FA_M2));
          pv[i] = (kb + i <= qg) ? e : 0.f;
        }
        l_ += (pv[0] + pv[1]) + (pv[2] + pv[3]);
        pf[kt] = (bf16x4){f2bf(pv[0]), f2bf(pv[1]), f2bf(pv[2]), f2bf(pv[3])};
      }
    } else {
#pragma unroll
      for (int kt = 0; kt < 2; ++kt) {
        float pv[4];
#pragma unroll
        for (int i = 0; i < 4; ++i)
          pv[i] = fexp2(fmaf(sA[kt][i], FA_SCL2, -FA_M2));
        l_ += (pv[0] + pv[1]) + (pv[2] + pv[3]);
        pf[kt] = (bf16x4){f2bf(pv[0]), f2bf(pv[1]), f2bf(pv[2]), f2bf(pv[3])};
      }
    }

    // PV(tt): O^T += V^T · P^T — single K=32 MFMA per ht
    {
      const bf16* Vb = VS[vRead];
      const bf16x8 pcat = __builtin_shufflevector(pf[0], pf[1], 0, 1, 2, 3, 4, 5, 6, 7);
#pragma unroll
      for (int ht = 0; ht < 8; ++ht) {
        bf16x8 vf8 = *(const bf16x8*)(Vb + ht * 512 + lane * 8);
        o[ht] = mfma32k(vf8, pcat, o[ht]);
      }
    }

    // exact-count wait: only THIS iter's stages may remain outstanding
    if (sk)      asm volatile("s_waitcnt vmcnt(4)\n\ts_barrier" ::: "memory");
    else if (sv) asm volatile("s_waitcnt vmcnt(2)\n\ts_barrier" ::: "memory");
    else         asm volatile("s_waitcnt vmcnt(0)\n\ts_barrier" ::: "memory");

    sA[0] = sB[0]; sA[1] = sB[1];
    kStage = (kStage == 2) ? 0 : kStage + 1;
    kNext  = (kNext == 2) ? 0 : kNext + 1;
    vRead  = (vRead == 2) ? 0 : vRead + 1;
    vStage = (vStage == 2) ? 0 : vStage + 1;
  }

  // epilogue: reduce l over key-quads, scale, direct store
  {
    float lv = l_;
    lv += __shfl_xor(lv, 16);
    lv += __shfl_xor(lv, 32);
    const float rl = 1.f / lv;
    const size_t rbase = (size_t)(b * T_ + myq0 + colL) * (H_ * HD_) + h * HD_;
#pragma unroll
    for (int ht = 0; ht < 8; ++ht) {
      bf16x4 ov;
#pragma unroll
      for (int i = 0; i < 4; ++i) ov[i] = f2bf(o[ht][i] * rl);
      *(bf16x4*)(ao + rbase + ht * 16 + quad * 4) = ov;
    }
  }
}

// ---------------------------------------------------------------------------
extern "C" void kernel_launch(void* const* d_in, const int* in_sizes, int n_in,
                              void* d_out, int out_size, void* d_ws, size_t ws_size,
                              hipStream_t stream) {
  (void)in_sizes; (void)n_in; (void)out_size; (void)ws_size;
  const float* x  = (const float*)d_in[0];
  const float* wq = (const float*)d_in[1];
  const float* bq = (const float*)d_in[2];
  const float* wk = (const float*)d_in[3];
  const float* bk = (const float*)d_in[4];
  const float* wv = (const float*)d_in[5];
  const float* bv = (const float*)d_in[6];
  const float* wo = (const float*)d_in[7];
  float* out = (float*)d_out;

  char* ws = (char*)d_ws;
  bf16* xb    = (bf16*)ws;                 // 16 MiB; reused as ao after QKV gemm
  bf16* wqkvT = (bf16*)(ws + (16u << 20)); // 12 MiB [3072][2048]
  bf16* woT   = (bf16*)(ws + (28u << 20)); //  8 MiB [2048][2048]
  bf16* qkv   = (bf16*)(ws + (36u << 20)); // 24 MiB [4096][3072] (pre-rope Q/K)
  bf16* kp    = (bf16*)(ws + (60u << 20)); //  8 MiB fragment-major roped K'
  bf16* vp    = (bf16*)(ws + (68u << 20)); //  8 MiB fragment-major V'
  float2* tab = (float2*)(ws + (76u << 20)); // 1 MiB RoPE cos/sin [2048][64]

  // 1: all independent prep (cast, weight transposes, rope table)
  prep_kernel<<<dim3(18944), dim3(256), 0, stream>>>(
      x, xb, wq, wk, wv, wqkvT, wo, woT, tab);

  // 2: fused QKV projection — 8-phase 256² deep-pipelined GEMM
  gemm_qkv8<<<dim3(NQKV / 256, MROWS / 256), dim3(512), 0, stream>>>(
      xb, wqkvT, qkv, bq, bk, bv, MROWS, NQKV, C_);

  // 3: K rope+pack, V pack (one launch)
  pack_kv<<<dim3(1024), dim3(256), 0, stream>>>(qkv, kp, vp, tab);

  // 4: flash attention (Q roped in registers)
  bf16* ao = xb;
  flash_mfma8<<<dim3(1024), dim3(256), 0, stream>>>(qkv, kp, vp, ao, tab);

  // 5: output projection, fp32 out (m97 structure: 512 blocks = 2/CU)
  gemm_mfma<false><<<dim3(C_ / 128, MROWS / 128), dim3(256), 0, stream>>>(
      ao, woT, out, nullptr, nullptr, nullptr, MROWS, C_, KOFF);
}

// Round 5
// 311.113 us; speedup vs baseline: 1.0014x; 1.0014x over previous
//
#include <hip/hip_runtime.h>
#include <hip/hip_bf16.h>
#include <math.h>

#define B_ 2
#define T_ 2048
#define C_ 2048
#define H_ 16
#define KVH_ 4
#define HD_ 128
#define G_ (H_ / KVH_)
#define MROWS (B_ * T_)                    // 4096
#define NQKV (H_ * HD_ + 2 * KVH_ * HD_)   // 3072
#define KOFF (H_ * HD_)                    // 2048
#define VOFF (H_ * HD_ + KVH_ * HD_)       // 2560
#define L2T (13.287712379549449f / 64.0f)  // log2(10000)/64

typedef __hip_bfloat16 bf16;
typedef short bf16x8 __attribute__((ext_vector_type(8)));   // 8 bf16 = 4 VGPR
typedef short bf16x4 __attribute__((ext_vector_type(4)));   // 4 bf16 = 2 VGPR
typedef float f32x4 __attribute__((ext_vector_type(4)));

__device__ __forceinline__ void gload_lds16(const void* g, void* l) {
  __builtin_amdgcn_global_load_lds(
      (const __attribute__((address_space(1))) unsigned int*)g,
      (__attribute__((address_space(3))) unsigned int*)l, 16, 0, 0);
}

static __device__ __forceinline__ f32x4 mfma32k(bf16x8 a, bf16x8 b, f32x4 c) {
  return __builtin_amdgcn_mfma_f32_16x16x32_bf16(a, b, c, 0, 0, 0);
}

// fast RNE f32->bf16 (no NaN handling; inputs are finite)
static __device__ __forceinline__ short f2bf(float x) {
  unsigned u = __builtin_bit_cast(unsigned, x);
  u += 0x7FFFu + ((u >> 16) & 1u);
  return (short)(u >> 16);
}

// bf16 (raw short) -> f32
static __device__ __forceinline__ float bfh2f(short h) {
  unsigned u = ((unsigned)(unsigned short)h) << 16;
  return __builtin_bit_cast(float, u);
}

static __device__ __forceinline__ float fexp2(float x) {
#if __has_builtin(__builtin_amdgcn_exp2f)
  return __builtin_amdgcn_exp2f(x);
#else
  return exp2f(x);
#endif
}

// ---------------------------------------------------------------------------
// Fused prep: [0,8192)   cast x fp32->bf16
//             [8192,14336)  wq|wk|wv transpose-cast -> wqkvT [3072][2048]
//             [14336,18432) wo transpose-cast -> woT [2048][2048]
//             [18432,18944) RoPE cos/sin table [2048][64] float2
// ---------------------------------------------------------------------------
__global__ __launch_bounds__(256) void prep_kernel(
    const float* __restrict__ x, bf16* __restrict__ xb,
    const float* __restrict__ wq, const float* __restrict__ wk,
    const float* __restrict__ wv, bf16* __restrict__ wqkvT,
    const float* __restrict__ wo, bf16* __restrict__ woT,
    float2* __restrict__ tab) {
  __shared__ float t[32][33];
  int bid = blockIdx.x;
  if (bid < 8192) {                        // ---- cast x
    const int i = (bid * 256 + threadIdx.x) * 4;
    float4 v = *(const float4*)(x + i);
    xb[i + 0] = __float2bfloat16(v.x);
    xb[i + 1] = __float2bfloat16(v.y);
    xb[i + 2] = __float2bfloat16(v.z);
    xb[i + 3] = __float2bfloat16(v.w);
    return;
  }
  bid -= 8192;
  if (bid < 6144) {                        // ---- qkv weight transpose
    const int tx = threadIdx.x & 31, ty = threadIdx.x >> 5;
    const int c0 = (bid % 96) * 32;        // fused n-dim 0..3071
    const int r0 = (bid / 96) * 32;        // k-dim
    const float* src;
    int nn, ld;
    if (c0 < KOFF)      { src = wq; nn = c0;        ld = 2048; }
    else if (c0 < VOFF) { src = wk; nn = c0 - KOFF; ld = 512; }
    else                { src = wv; nn = c0 - VOFF; ld = 512; }
#pragma unroll
    for (int it = 0; it < 4; ++it)
      t[ty + 8 * it][tx] = src[(size_t)(r0 + ty + 8 * it) * ld + nn + tx];
    __syncthreads();
#pragma unroll
    for (int it = 0; it < 4; ++it)
      wqkvT[(size_t)(c0 + ty + 8 * it) * 2048 + r0 + tx] =
          __float2bfloat16(t[tx][ty + 8 * it]);
    return;
  }
  bid -= 6144;
  if (bid < 4096) {                        // ---- wo transpose
    const int tx = threadIdx.x & 31, ty = threadIdx.x >> 5;
    const int c0 = (bid & 63) * 32;
    const int r0 = (bid >> 6) * 32;
#pragma unroll
    for (int it = 0; it < 4; ++it)
      t[ty + 8 * it][tx] = wo[(size_t)(r0 + ty + 8 * it) * 2048 + c0 + tx];
    __syncthreads();
#pragma unroll
    for (int it = 0; it < 4; ++it)
      woT[(size_t)(c0 + ty + 8 * it) * 2048 + r0 + tx] =
          __float2bfloat16(t[tx][ty + 8 * it]);
    return;
  }
  bid -= 4096;
  {                                        // ---- RoPE table
    const int idx = bid * 256 + threadIdx.x;   // [0, 131072)
    const int tt = idx >> 6, i = idx & 63;
    const float invf = fexp2(-(float)i * L2T);
    float s, c;
    __sincosf((float)tt * invf, &s, &c);
    tab[idx] = make_float2(c, s);
  }
}

// ---------------------------------------------------------------------------
// Fused pack (PV-mfma32 layout, r4):
// K chunk ((bk*64 + tile)*8 + kt*4 + c)*512 + L*8 holds (RoPE'd)
//   K[b, t = tile*32 + ((L>>2)&3)*8 + kt*4 + (L&3), kvh][c*32 + (L>>4)*8 ..+8]
//   => QK output sA[kt] row m=quad*4+i corresponds to key quad*8 + kt*4 + i.
// V chunk ((bk*64 + tile)*8 + ht)*512 + L*8 holds
//   V[b, t = tile*32 + (L>>4)*8 + j, kvh][ht*16 + (L&15)]  (j = 0..7)
//   => exact A-operand of mfma_16x16x32 for PV (k = quad*8 + j).
// ---------------------------------------------------------------------------
__global__ __launch_bounds__(256) void pack_kv(const bf16* __restrict__ qkv,
                                               bf16* __restrict__ kp,
                                               bf16* __restrict__ vp,
                                               const float2* __restrict__ tab) {
  const int pid = blockIdx.x;
  if (pid < 512) {                         // ---- K with RoPE
    const int tile = pid & 63;
    const int bk = pid >> 6;               // b*KVH + kvh
    const int b = bk >> 2, kvh = bk & 3;
#pragma unroll
    for (int u = 0; u < 2; ++u) {
      const int t = threadIdx.x + u * 256; // chunk id 0..511
      const int kc = t >> 6, L = t & 63;
      const int trow = tile * 32 + ((L >> 2) & 3) * 8 + (kc >> 2) * 4 + (L & 3);
      const bf16* src = qkv + (size_t)(b * T_ + trow) * NQKV +
                        KOFF + kvh * HD_ + (kc & 3) * 32 + (L >> 4) * 8;
      bf16x8 vs = *(const bf16x8*)src;
      bf16x8 vpair = *(const bf16x8*)(src + (((kc & 2) == 0) ? 64 : -64));
      const float2* tp = tab + trow * 64 + (kc & 1) * 32 + (L >> 4) * 8;
      bf16x8 outv;
#pragma unroll
      for (int jj = 0; jj < 8; ++jj) {
        const float2 cs = tp[jj];
        const float a = bfh2f(vs[jj]), p = bfh2f(vpair[jj]);
        outv[jj] = f2bf(((kc & 2) == 0) ? (a * cs.x - p * cs.y)
                                        : (a * cs.x + p * cs.y));
      }
      *(bf16x8*)(kp + ((size_t)(bk * 64 + tile) * 8 + kc) * 512 + L * 8) = outv;
    }
    return;
  }
  {                                        // ---- V pack (no rope)
    const int pid2 = pid - 512;
    const int tile = pid2 & 63;
    const int bk = pid2 >> 6;
    const int b = bk >> 2, kvh = bk & 3;
#pragma unroll
    for (int u = 0; u < 2; ++u) {
      const int t = threadIdx.x + u * 256;
      const int ht = t >> 6, L = t & 63;
      const int colL = L & 15, quad = L >> 4;
      const bf16* base = qkv + (size_t)(b * T_ + tile * 32 + quad * 8) * NQKV +
                         VOFF + kvh * HD_ + ht * 16 + colL;
      bf16x8 v;
#pragma unroll
      for (int jj = 0; jj < 8; ++jj)
        v[jj] = *(const short*)(base + (size_t)jj * NQKV);
      *(bf16x8*)(vp + ((size_t)(bk * 64 + tile) * 8 + ht) * 512 + L * 8) = v;
    }
  }
}

// ---------------------------------------------------------------------------
// 8-phase 256xBNxBK=64 MFMA GEMM (T2+T3+T4+T5), BN = NF*64 chosen so the grid
// is EXACTLY 256 blocks = 1/CU (r4 lesson: 256-tile at 192 blocks idles 25%
// of the machine). NF=3 (BN=192) for QKV (16x16 grid), NF=2 (BN=128) for the
// out-projection (16x16 grid). 512 thr = 8 waves (2M x 4N); per-wave C =
// 128 x NF*16; acc[8][NF]; LDS = 2 bufs x (A 32KB + B NF*8KB) = 112/96KB.
// 4 phases/K-tile: (mh,ks) in {(0,0),(1,0),(0,1),(1,1)}, 4*NF MFMA each,
// setprio-wrapped, 2 barriers/phase.
// T2 swizzle (BK=64 -> 8 x 16B slots/row): read slot' = (ks*4+quad)^(row&7)
// (row&7 == colL&7 for all fragment rows); write side stays LINEAR for
// global_load_lds with the same involution pre-applied to the global source
// k-slot ((L&7)^(L>>3); each gload covers an 8-row-aligned group).
// Prefetch of tile t+1 spread over phases: p1:[Aq0,Aq2] p2:[Bq0,Bq1]
// p3:[(Bq2 if NF==3), Aq1] p4:[Aq3]. Per-wave FIFO ledger (both NF):
//   tile order = [A0,A2,B0..B(NF-1),A1,A3]; p1 needs first 4+(NF-2), p2 needs
//   A1,A3. vmcnt(2) at p1-end (leaves the 2 p1-prefetches in flight) and
//   vmcnt(2) at p4-end (leaves A1,A3(t+1)). Never 0 in steady state.
// Buf parity: reads hit buf (t&1), stages write buf (t&1)^1 -> no WAR hazard.
// ---------------------------------------------------------------------------
template <int NF, bool BF16OUT>
__global__ __launch_bounds__(512, 1) void gemm8(
    const bf16* __restrict__ A, const bf16* __restrict__ Bt, void* __restrict__ Cout,
    const float* __restrict__ bq, const float* __restrict__ bk2,
    const float* __restrict__ bv2, int M, int N, int K) {
  constexpr int BN = NF * 64;
  __shared__ __align__(16) bf16 As[2][256 * 64];   // 64KB
  __shared__ __align__(16) bf16 Bs[2][BN * 64];    // NF*16KB
  const int tid = threadIdx.x;
  const int w = tid >> 6, lane = tid & 63;
  const int colL = lane & 15, quad = lane >> 4;
  const int wm = w >> 2, wn = w & 3;
  const int r0 = blockIdx.y * 256, c0 = blockIdx.x * BN;
  const int c7 = colL & 7;
  const int sl0 = (quad ^ c7) * 8;            // swizzled 16B-slot (elem), ks=0
  const int sl1 = ((quad + 4) ^ c7) * 8;      // ks=1
  const int lrow = lane >> 3;                 // src row within 8-row group
  const int lsl = ((lane & 7) ^ lrow) * 8;    // pre-swizzled src k-elems
  const int nk = K >> 6;

  const bf16* pa = A + (size_t)(r0 + w * 8 + lrow) * K + lsl;
  const bf16* pb = Bt + (size_t)(c0 + w * 8 + lrow) * K + lsl;

  auto stA = [&](int kt, int bi, int q) {   // stage 64-row quarter q of A
    gload_lds16(pa + (size_t)q * 64 * K + kt * 64, &As[bi][(q * 64 + w * 8) * 64]);
  };
  auto stB = [&](int kt, int bi, int q) {
    gload_lds16(pb + (size_t)q * 64 * K + kt * 64, &Bs[bi][(q * 64 + w * 8) * 64]);
  };

  f32x4 acc[8][NF];
  const f32x4 zero = {0.f, 0.f, 0.f, 0.f};
#pragma unroll
  for (int m = 0; m < 8; ++m)
#pragma unroll
    for (int n = 0; n < NF; ++n) acc[m][n] = zero;

  // prologue: tile 0 in ledger order [A0,A2,B0..B(NF-1),A1,A3]
  stA(0, 0, 0); stA(0, 0, 2);
  stB(0, 0, 0); stB(0, 0, 1);
  if constexpr (NF == 3) stB(0, 0, 2);
  stA(0, 0, 1); stA(0, 0, 3);
  asm volatile("s_waitcnt vmcnt(2)" ::: "memory");
  __builtin_amdgcn_s_barrier();

#pragma unroll 1
  for (int t = 0; t < nk; ++t) {
    const int bi = t & 1, nb = bi ^ 1;
    const bool st = (t + 1 < nk);
    const bf16* Ab = &As[bi][(wm * 128 + colL) * 64];
    const bf16* Bb = &Bs[bi][(wn * (NF * 16) + colL) * 64];
    bf16x8 afr[4], bfr[NF];

    // ---- p1: (mh0, ks0) + B(ks0); stage Aq0,Aq2(t+1); vmcnt(2) at end
#pragma unroll
    for (int m = 0; m < 4; ++m) afr[m] = *(const bf16x8*)(Ab + m * 16 * 64 + sl0);
#pragma unroll
    for (int n = 0; n < NF; ++n) bfr[n] = *(const bf16x8*)(Bb + n * 16 * 64 + sl0);
    if (st) { stA(t + 1, nb, 0); stA(t + 1, nb, 2); }
    __builtin_amdgcn_s_barrier();
    __builtin_amdgcn_s_setprio(1);
#pragma unroll
    for (int m = 0; m < 4; ++m)
#pragma unroll
      for (int n = 0; n < NF; ++n) acc[m][n] = mfma32k(afr[m], bfr[n], acc[m][n]);
    __builtin_amdgcn_s_setprio(0);
    if (st) asm volatile("s_waitcnt vmcnt(2)" ::: "memory");
    else    asm volatile("s_waitcnt vmcnt(0)" ::: "memory");
    __builtin_amdgcn_s_barrier();

    // ---- p2: (mh1, ks0); stage Bq0,Bq1(t+1)
#pragma unroll
    for (int m = 0; m < 4; ++m)
      afr[m] = *(const bf16x8*)(Ab + (64 + m * 16) * 64 + sl0);
    if (st) { stB(t + 1, nb, 0); stB(t + 1, nb, 1); }
    __builtin_amdgcn_s_barrier();
    __builtin_amdgcn_s_setprio(1);
#pragma unroll
    for (int m = 0; m < 4; ++m)
#pragma unroll
      for (int n = 0; n < NF; ++n) acc[m + 4][n] = mfma32k(afr[m], bfr[n], acc[m + 4][n]);
    __builtin_amdgcn_s_setprio(0);
    __builtin_amdgcn_s_barrier();

    // ---- p3: (mh0, ks1) + B(ks1); stage (Bq2 if NF==3), Aq1(t+1)
#pragma unroll
    for (int m = 0; m < 4; ++m) afr[m] = *(const bf16x8*)(Ab + m * 16 * 64 + sl1);
#pragma unroll
    for (int n = 0; n < NF; ++n) bfr[n] = *(const bf16x8*)(Bb + n * 16 * 64 + sl1);
    if (st) {
      if constexpr (NF == 3) stB(t + 1, nb, 2);
      stA(t + 1, nb, 1);
    }
    __builtin_amdgcn_s_barrier();
    __builtin_amdgcn_s_setprio(1);
#pragma unroll
    for (int m = 0; m < 4; ++m)
#pragma unroll
      for (int n = 0; n < NF; ++n) acc[m][n] = mfma32k(afr[m], bfr[n], acc[m][n]);
    __builtin_amdgcn_s_setprio(0);
    __builtin_amdgcn_s_barrier();

    // ---- p4: (mh1, ks1); stage Aq3(t+1); vmcnt(2) at end
#pragma unroll
    for (int m = 0; m < 4; ++m)
      afr[m] = *(const bf16x8*)(Ab + (64 + m * 16) * 64 + sl1);
    if (st) stA(t + 1, nb, 3);
    __builtin_amdgcn_s_barrier();
    __builtin_amdgcn_s_setprio(1);
#pragma unroll
    for (int m = 0; m < 4; ++m)
#pragma unroll
      for (int n = 0; n < NF; ++n) acc[m + 4][n] = mfma32k(afr[m], bfr[n], acc[m + 4][n]);
    __builtin_amdgcn_s_setprio(0);
    if (st) asm volatile("s_waitcnt vmcnt(2)" ::: "memory");
    __builtin_amdgcn_s_barrier();
  }

  // epilogue: (bias +) store
#pragma unroll
  for (int nt = 0; nt < NF; ++nt) {
    const int c = c0 + wn * (NF * 16) + nt * 16 + colL;
    float bias = 0.f;
    if (bq) bias = (c < KOFF) ? bq[c] : (c < VOFF ? bk2[c - KOFF] : bv2[c - VOFF]);
#pragma unroll
    for (int mt = 0; mt < 8; ++mt) {
#pragma unroll
      for (int i = 0; i < 4; ++i) {
        const int r = r0 + wm * 128 + mt * 16 + quad * 4 + i;
        const float v = acc[mt][nt][i] + bias;
        if (BF16OUT)
          ((bf16*)Cout)[(size_t)r * N + c] = __float2bfloat16(v);
        else
          ((float*)Cout)[(size_t)r * N + c] = v;
      }
    }
  }
}

// ---------------------------------------------------------------------------
// Causal GQA flash attention v11: PV as single mfma_16x16x32 per ht.
// Block = 256 thr = 4 waves = the 4 q-heads of one kv group; all waves share
// the SAME 16 q-rows and kv stream. K/V tiles (fragment-major packed) staged
// via global_load_lds into triple buffers (48KB): K prefetched at distance 3,
// V at distance 2; exact-count vmcnt(4/2/0)+s_barrier per tile. QK(t+1) is
// issued BEFORE softmax(t)/PV(t). 1024 blocks, 3/CU, descending work order
// (LPT balance); bk = id&7 keeps kv streams XCD-local. Q RoPE'd in registers
// from the prep table. Key->MFMA-row permutation (pack_kv r4) makes lane quad
// hold keys quad*8..+7 so concat(pf[0],pf[1]) is the exact B-operand and the
// repacked V fragment the exact A-operand of one K=32 MFMA per ht.
// Fixed-max softmax (exact, verified r3).
// ---------------------------------------------------------------------------
#define FA_SCL2 (0.08838834764831845f * 1.4426950408889634f)  // scale * log2(e)
#define FA_M2 16.0f                                           // fixed max (exp2 domain)

__global__ __launch_bounds__(256, 3) void flash_mfma8(
    const bf16* __restrict__ qkv, const bf16* __restrict__ kp,
    const bf16* __restrict__ vp, bf16* __restrict__ ao,
    const float2* __restrict__ tab) {
  __shared__ __align__(16) bf16 KS[3][4096];   // 3 x 8KB
  __shared__ __align__(16) bf16 VS[3][4096];   // 3 x 8KB

  const int id = blockIdx.x;
  const int bk = id & 7;                   // b*KVH + kvh  (== XCD id under %8 rr)
  const int u = id >> 3;                   // 0..127
  const int jq = 127 - u;                  // descending work order (LPT)
  const int b = bk >> 2, kvh = bk & 3;
  const int w = threadIdx.x >> 6;          // wave = q-head within group
  const int h = (kvh << 2) | w;
  const int lane = threadIdx.x & 63;
  const int colL = lane & 15, quad = lane >> 4;
  const int myq0 = jq * 16;                // 16 q-rows per block
  const int nkv = (jq >> 1) + 1;           // 32-row kv tiles covering causal range

  const bf16* kpt = kp + ((size_t)(bk * 64)) * 4096 + (w * 2) * 512 + lane * 8;
  const bf16* vpt = vp + ((size_t)(bk * 64)) * 4096 + (w * 2) * 512 + lane * 8;

  auto stageK = [&](int tile, int slot) {
    const bf16* s = kpt + (size_t)tile * 4096;
    bf16* d = &KS[slot][(w * 2) * 512];    // wave-uniform base; HW adds lane*16B
    gload_lds16(s, d);
    gload_lds16(s + 512, d + 512);
  };
  auto stageV = [&](int tile, int slot) {
    const bf16* s = vpt + (size_t)tile * 4096;
    bf16* d = &VS[slot][(w * 2) * 512];
    gload_lds16(s, d);
    gload_lds16(s + 512, d + 512);
  };

  // Q fragments (B-operand of K·Q^T), RoPE'd in registers.
  bf16x8 qf[4];
  {
    const bf16* qg = qkv + (size_t)(b * T_ + myq0) * NQKV + h * HD_;
    bf16x8 rq[4];
#pragma unroll
    for (int c = 0; c < 4; ++c)
      rq[c] = *(const bf16x8*)(qg + (size_t)colL * NQKV + c * 32 + quad * 8);
    const float2* tp = tab + (myq0 + colL) * 64 + quad * 8;
    float2 cs0[8], cs1[8];
#pragma unroll
    for (int jj = 0; jj < 8; ++jj) { cs0[jj] = tp[jj]; cs1[jj] = tp[32 + jj]; }
#pragma unroll
    for (int c = 0; c < 4; ++c) {
#pragma unroll
      for (int jj = 0; jj < 8; ++jj) {
        const float2 cs = (c & 1) ? cs1[jj] : cs0[jj];
        const float a = bfh2f(rq[c][jj]), p = bfh2f(rq[c ^ 2][jj]);
        qf[c][jj] = f2bf((c & 2) ? (a * cs.x + p * cs.y)
                                 : (a * cs.x - p * cs.y));
      }
    }
  }

  const f32x4 zero = {0.f, 0.f, 0.f, 0.f};
  auto qk = [&](const bf16* Kb, f32x4 (&s_)[2]) {
    s_[0] = zero; s_[1] = zero;
#pragma unroll
    for (int c = 0; c < 4; ++c) {
      bf16x8 kf0 = *(const bf16x8*)(Kb + c * 512 + lane * 8);
      bf16x8 kf1 = *(const bf16x8*)(Kb + (4 + c) * 512 + lane * 8);
      s_[0] = mfma32k(kf0, qf[c], s_[0]);
      s_[1] = mfma32k(kf1, qf[c], s_[1]);
    }
  };

  f32x4 o[8];
#pragma unroll
  for (int ht = 0; ht < 8; ++ht) o[ht] = zero;
  float l_ = 0.f;

  // prologue: K tiles 0..2, V tiles 0..1; full drain; QK(0)
  stageK(0, 0);
  if (nkv > 1) stageK(1, 1);
  if (nkv > 2) stageK(2, 2);
  stageV(0, 0);
  if (nkv > 1) stageV(1, 1);
  asm volatile("s_waitcnt vmcnt(0)\n\ts_barrier" ::: "memory");

  f32x4 sA[2], sB[2];
  qk(KS[0], sA);

  int kStage = 0, kNext = 1, vRead = 0, vStage = 2;
#pragma unroll 1
  for (int tt = 0; tt < nkv; ++tt) {
    const bool sk = (tt + 3 < nkv), sv = (tt + 2 < nkv);
    if (sk) stageK(tt + 3, kStage);        // overwrites K(tt) slot: dead since iter tt-1
    if (sv) stageV(tt + 2, vStage);        // overwrites V(tt-1) slot: dead

    // QK(t+1) first: MFMA pipe busy while VALU does softmax(t)
    if (tt + 1 < nkv) qk(KS[kNext], sB);

    // softmax on sA (tile tt); key-in-frame = quad*8 + kt*4 + i (r4 mapping)
    bf16x4 pf[2];
    if (tt == nkv - 1) {
      const int qg = ((jq & 1) << 4) | colL;   // q offset within 32-row kv frame
#pragma unroll
      for (int kt = 0; kt < 2; ++kt) {
        const int kb = quad * 8 + kt * 4;
        float pv[4];
#pragma unroll
        for (int i = 0; i < 4; ++i) {
          float e = fexp2(fmaf(sA[kt][i], FA_SCL2, -FA_M2));
          pv[i] = (kb + i <= qg) ? e : 0.f;
        }
        l_ += (pv[0] + pv[1]) + (pv[2] + pv[3]);
        pf[kt] = (bf16x4){f2bf(pv[0]), f2bf(pv[1]), f2bf(pv[2]), f2bf(pv[3])};
      }
    } else {
#pragma unroll
      for (int kt = 0; kt < 2; ++kt) {
        float pv[4];
#pragma unroll
        for (int i = 0; i < 4; ++i)
          pv[i] = fexp2(fmaf(sA[kt][i], FA_SCL2, -FA_M2));
        l_ += (pv[0] + pv[1]) + (pv[2] + pv[3]);
        pf[kt] = (bf16x4){f2bf(pv[0]), f2bf(pv[1]), f2bf(pv[2]), f2bf(pv[3])};
      }
    }

    // PV(tt): O^T += V^T · P^T — single K=32 MFMA per ht
    {
      const bf16* Vb = VS[vRead];
      const bf16x8 pcat = __builtin_shufflevector(pf[0], pf[1], 0, 1, 2, 3, 4, 5, 6, 7);
#pragma unroll
      for (int ht = 0; ht < 8; ++ht) {
        bf16x8 vf8 = *(const bf16x8*)(Vb + ht * 512 + lane * 8);
        o[ht] = mfma32k(vf8, pcat, o[ht]);
      }
    }

    // exact-count wait: only THIS iter's stages may remain outstanding
    if (sk)      asm volatile("s_waitcnt vmcnt(4)\n\ts_barrier" ::: "memory");
    else if (sv) asm volatile("s_waitcnt vmcnt(2)\n\ts_barrier" ::: "memory");
    else         asm volatile("s_waitcnt vmcnt(0)\n\ts_barrier" ::: "memory");

    sA[0] = sB[0]; sA[1] = sB[1];
    kStage = (kStage == 2) ? 0 : kStage + 1;
    kNext  = (kNext == 2) ? 0 : kNext + 1;
    vRead  = (vRead == 2) ? 0 : vRead + 1;
    vStage = (vStage == 2) ? 0 : vStage + 1;
  }

  // epilogue: reduce l over key-quads, scale, direct store
  {
    float lv = l_;
    lv += __shfl_xor(lv, 16);
    lv += __shfl_xor(lv, 32);
    const float rl = 1.f / lv;
    const size_t rbase = (size_t)(b * T_ + myq0 + colL) * (H_ * HD_) + h * HD_;
#pragma unroll
    for (int ht = 0; ht < 8; ++ht) {
      bf16x4 ov;
#pragma unroll
      for (int i = 0; i < 4; ++i) ov[i] = f2bf(o[ht][i] * rl);
      *(bf16x4*)(ao + rbase + ht * 16 + quad * 4) = ov;
    }
  }
}

// ---------------------------------------------------------------------------
extern "C" void kernel_launch(void* const* d_in, const int* in_sizes, int n_in,
                              void* d_out, int out_size, void* d_ws, size_t ws_size,
                              hipStream_t stream) {
  (void)in_sizes; (void)n_in; (void)out_size; (void)ws_size;
  const float* x  = (const float*)d_in[0];
  const float* wq = (const float*)d_in[1];
  const float* bq = (const float*)d_in[2];
  const float* wk = (const float*)d_in[3];
  const float* bk = (const float*)d_in[4];
  const float* wv = (const float*)d_in[5];
  const float* bv = (const float*)d_in[6];
  const float* wo = (const float*)d_in[7];
  float* out = (float*)d_out;

  char* ws = (char*)d_ws;
  bf16* xb    = (bf16*)ws;                 // 16 MiB; reused as ao after QKV gemm
  bf16* wqkvT = (bf16*)(ws + (16u << 20)); // 12 MiB [3072][2048]
  bf16* woT   = (bf16*)(ws + (28u << 20)); //  8 MiB [2048][2048]
  bf16* qkv   = (bf16*)(ws + (36u << 20)); // 24 MiB [4096][3072] (pre-rope Q/K)
  bf16* kp    = (bf16*)(ws + (60u << 20)); //  8 MiB fragment-major roped K'
  bf16* vp    = (bf16*)(ws + (68u << 20)); //  8 MiB fragment-major V'
  float2* tab = (float2*)(ws + (76u << 20)); // 1 MiB RoPE cos/sin [2048][64]

  // 1: all independent prep (cast, weight transposes, rope table)
  prep_kernel<<<dim3(18944), dim3(256), 0, stream>>>(
      x, xb, wq, wk, wv, wqkvT, wo, woT, tab);

  // 2: fused QKV projection — 8-phase 256x192 GEMM, 16x16 = 256 blocks (1/CU)
  gemm8<3, true><<<dim3(16, 16), dim3(512), 0, stream>>>(
      xb, wqkvT, qkv, bq, bk, bv, MROWS, NQKV, C_);

  // 3: K rope+pack, V pack (one launch)
  pack_kv<<<dim3(1024), dim3(256), 0, stream>>>(qkv, kp, vp, tab);

  // 4: flash attention (Q roped in registers)
  bf16* ao = xb;
  flash_mfma8<<<dim3(1024), dim3(256), 0, stream>>>(qkv, kp, vp, ao, tab);

  // 5: output projection — 8-phase 256x128 GEMM, 16x16 = 256 blocks (1/CU)
  gemm8<2, false><<<dim3(16, 16), dim3(512), 0, stream>>>(
      ao, woT, out, nullptr, nullptr, nullptr, MROWS, C_, KOFF);
}

// Round 6
// 303.947 us; speedup vs baseline: 1.0250x; 1.0236x over previous
//
#include <hip/hip_runtime.h>
#include <hip/hip_bf16.h>
#include <math.h>

#define B_ 2
#define T_ 2048
#define C_ 2048
#define H_ 16
#define KVH_ 4
#define HD_ 128
#define G_ (H_ / KVH_)
#define MROWS (B_ * T_)                    // 4096
#define NQKV (H_ * HD_ + 2 * KVH_ * HD_)   // 3072
#define KOFF (H_ * HD_)                    // 2048
#define VOFF (H_ * HD_ + KVH_ * HD_)       // 2560
#define L2T (13.287712379549449f / 64.0f)  // log2(10000)/64

typedef __hip_bfloat16 bf16;
typedef short bf16x8 __attribute__((ext_vector_type(8)));   // 8 bf16 = 4 VGPR
typedef short bf16x4 __attribute__((ext_vector_type(4)));   // 4 bf16 = 2 VGPR
typedef float f32x4 __attribute__((ext_vector_type(4)));

__device__ __forceinline__ void gload_lds16(const void* g, void* l) {
  __builtin_amdgcn_global_load_lds(
      (const __attribute__((address_space(1))) unsigned int*)g,
      (__attribute__((address_space(3))) unsigned int*)l, 16, 0, 0);
}

static __device__ __forceinline__ f32x4 mfma32k(bf16x8 a, bf16x8 b, f32x4 c) {
  return __builtin_amdgcn_mfma_f32_16x16x32_bf16(a, b, c, 0, 0, 0);
}

// fast RNE f32->bf16 (no NaN handling; inputs are finite)
static __device__ __forceinline__ short f2bf(float x) {
  unsigned u = __builtin_bit_cast(unsigned, x);
  u += 0x7FFFu + ((u >> 16) & 1u);
  return (short)(u >> 16);
}

// bf16 (raw short) -> f32
static __device__ __forceinline__ float bfh2f(short h) {
  unsigned u = ((unsigned)(unsigned short)h) << 16;
  return __builtin_bit_cast(float, u);
}

static __device__ __forceinline__ float fexp2(float x) {
#if __has_builtin(__builtin_amdgcn_exp2f)
  return __builtin_amdgcn_exp2f(x);
#else
  return exp2f(x);
#endif
}

// ---------------------------------------------------------------------------
// Fused prep: [0,8192)   cast x fp32->bf16
//             [8192,14336)  wq|wk|wv transpose-cast -> wqkvT [3072][2048]
//             [14336,18432) wo transpose-cast -> woT [2048][2048]
//             [18432,18944) RoPE cos/sin table [2048][64] float2
// ---------------------------------------------------------------------------
__global__ __launch_bounds__(256) void prep_kernel(
    const float* __restrict__ x, bf16* __restrict__ xb,
    const float* __restrict__ wq, const float* __restrict__ wk,
    const float* __restrict__ wv, bf16* __restrict__ wqkvT,
    const float* __restrict__ wo, bf16* __restrict__ woT,
    float2* __restrict__ tab) {
  __shared__ float t[32][33];
  int bid = blockIdx.x;
  if (bid < 8192) {                        // ---- cast x
    const int i = (bid * 256 + threadIdx.x) * 4;
    float4 v = *(const float4*)(x + i);
    xb[i + 0] = __float2bfloat16(v.x);
    xb[i + 1] = __float2bfloat16(v.y);
    xb[i + 2] = __float2bfloat16(v.z);
    xb[i + 3] = __float2bfloat16(v.w);
    return;
  }
  bid -= 8192;
  if (bid < 6144) {                        // ---- qkv weight transpose
    const int tx = threadIdx.x & 31, ty = threadIdx.x >> 5;
    const int c0 = (bid % 96) * 32;        // fused n-dim 0..3071
    const int r0 = (bid / 96) * 32;        // k-dim
    const float* src;
    int nn, ld;
    if (c0 < KOFF)      { src = wq; nn = c0;        ld = 2048; }
    else if (c0 < VOFF) { src = wk; nn = c0 - KOFF; ld = 512; }
    else                { src = wv; nn = c0 - VOFF; ld = 512; }
#pragma unroll
    for (int it = 0; it < 4; ++it)
      t[ty + 8 * it][tx] = src[(size_t)(r0 + ty + 8 * it) * ld + nn + tx];
    __syncthreads();
#pragma unroll
    for (int it = 0; it < 4; ++it)
      wqkvT[(size_t)(c0 + ty + 8 * it) * 2048 + r0 + tx] =
          __float2bfloat16(t[tx][ty + 8 * it]);
    return;
  }
  bid -= 6144;
  if (bid < 4096) {                        // ---- wo transpose
    const int tx = threadIdx.x & 31, ty = threadIdx.x >> 5;
    const int c0 = (bid & 63) * 32;
    const int r0 = (bid >> 6) * 32;
#pragma unroll
    for (int it = 0; it < 4; ++it)
      t[ty + 8 * it][tx] = wo[(size_t)(r0 + ty + 8 * it) * 2048 + c0 + tx];
    __syncthreads();
#pragma unroll
    for (int it = 0; it < 4; ++it)
      woT[(size_t)(c0 + ty + 8 * it) * 2048 + r0 + tx] =
          __float2bfloat16(t[tx][ty + 8 * it]);
    return;
  }
  bid -= 4096;
  {                                        // ---- RoPE table
    const int idx = bid * 256 + threadIdx.x;   // [0, 131072)
    const int tt = idx >> 6, i = idx & 63;
    const float invf = fexp2(-(float)i * L2T);
    float s, c;
    __sincosf((float)tt * invf, &s, &c);
    tab[idx] = make_float2(c, s);
  }
}

// ---------------------------------------------------------------------------
// Fused pack (PV-mfma32 layout, r4):
// K chunk ((bk*64 + tile)*8 + kt*4 + c)*512 + L*8 holds (RoPE'd)
//   K[b, t = tile*32 + ((L>>2)&3)*8 + kt*4 + (L&3), kvh][c*32 + (L>>4)*8 ..+8]
//   => QK output sA[kt] row m=quad*4+i corresponds to key quad*8 + kt*4 + i.
// V chunk ((bk*64 + tile)*8 + ht)*512 + L*8 holds
//   V[b, t = tile*32 + (L>>4)*8 + j, kvh][ht*16 + (L&15)]  (j = 0..7)
//   => exact A-operand of mfma_16x16x32 for PV (k = quad*8 + j).
// ---------------------------------------------------------------------------
__global__ __launch_bounds__(256) void pack_kv(const bf16* __restrict__ qkv,
                                               bf16* __restrict__ kp,
                                               bf16* __restrict__ vp,
                                               const float2* __restrict__ tab) {
  const int pid = blockIdx.x;
  if (pid < 512) {                         // ---- K with RoPE
    const int tile = pid & 63;
    const int bk = pid >> 6;               // b*KVH + kvh
    const int b = bk >> 2, kvh = bk & 3;
#pragma unroll
    for (int u = 0; u < 2; ++u) {
      const int t = threadIdx.x + u * 256; // chunk id 0..511
      const int kc = t >> 6, L = t & 63;
      const int trow = tile * 32 + ((L >> 2) & 3) * 8 + (kc >> 2) * 4 + (L & 3);
      const bf16* src = qkv + (size_t)(b * T_ + trow) * NQKV +
                        KOFF + kvh * HD_ + (kc & 3) * 32 + (L >> 4) * 8;
      bf16x8 vs = *(const bf16x8*)src;
      bf16x8 vpair = *(const bf16x8*)(src + (((kc & 2) == 0) ? 64 : -64));
      const float2* tp = tab + trow * 64 + (kc & 1) * 32 + (L >> 4) * 8;
      bf16x8 outv;
#pragma unroll
      for (int jj = 0; jj < 8; ++jj) {
        const float2 cs = tp[jj];
        const float a = bfh2f(vs[jj]), p = bfh2f(vpair[jj]);
        outv[jj] = f2bf(((kc & 2) == 0) ? (a * cs.x - p * cs.y)
                                        : (a * cs.x + p * cs.y));
      }
      *(bf16x8*)(kp + ((size_t)(bk * 64 + tile) * 8 + kc) * 512 + L * 8) = outv;
    }
    return;
  }
  {                                        // ---- V pack (no rope)
    const int pid2 = pid - 512;
    const int tile = pid2 & 63;
    const int bk = pid2 >> 6;
    const int b = bk >> 2, kvh = bk & 3;
#pragma unroll
    for (int u = 0; u < 2; ++u) {
      const int t = threadIdx.x + u * 256;
      const int ht = t >> 6, L = t & 63;
      const int colL = L & 15, quad = L >> 4;
      const bf16* base = qkv + (size_t)(b * T_ + tile * 32 + quad * 8) * NQKV +
                         VOFF + kvh * HD_ + ht * 16 + colL;
      bf16x8 v;
#pragma unroll
      for (int jj = 0; jj < 8; ++jj)
        v[jj] = *(const short*)(base + (size_t)jj * NQKV);
      *(bf16x8*)(vp + ((size_t)(bk * 64 + tile) * 8 + ht) * 512 + L * 8) = v;
    }
  }
}

// ---------------------------------------------------------------------------
// bf16 MFMA GEMM (m97 structure, proven best for these shapes — r5 showed the
// 8-phase 256-tile variants are ~7us slower here): C = A @ Bt^T (+ bias)
// ---------------------------------------------------------------------------
template <bool BF16OUT>
__global__ __launch_bounds__(256, 2) void gemm_mfma(
    const bf16* __restrict__ A, const bf16* __restrict__ Bt, void* __restrict__ Cout,
    const float* __restrict__ bq, const float* __restrict__ bk2,
    const float* __restrict__ bv2, int M, int N, int K) {
  __shared__ __align__(16) bf16 As[128 * 32];
  __shared__ __align__(16) bf16 Bs[128 * 32];
  const int tid = threadIdx.x;
  const int w = tid >> 6, lane = tid & 63;
  const int colL = lane & 15, quad = lane >> 4;
  const int wm = w & 1, wn = w >> 1;
  const int r0 = blockIdx.y * 128, c0 = blockIdx.x * 128;

  f32x4 acc[4][4];
  const f32x4 zero = {0.f, 0.f, 0.f, 0.f};
#pragma unroll
  for (int mt = 0; mt < 4; ++mt)
#pragma unroll
    for (int nt = 0; nt < 4; ++nt) acc[mt][nt] = zero;

  for (int k0 = 0; k0 < K; k0 += 32) {
    __syncthreads();
#pragma unroll
    for (int it = 0; it < 2; ++it) {
      const int seg = it * 4 + w;
      const int idx = seg * 64 + lane;
      const int row = idx >> 2, off = idx & 3;
      gload_lds16(A + (size_t)(r0 + row) * K + k0 + off * 8, &As[seg * 512]);
      gload_lds16(Bt + (size_t)(c0 + row) * K + k0 + off * 8, &Bs[seg * 512]);
    }
    __syncthreads();
    bf16x8 af[4], bfv[4];
#pragma unroll
    for (int mt = 0; mt < 4; ++mt)
      af[mt] = *(const bf16x8*)&As[(wm * 64 + mt * 16 + colL) * 32 + quad * 8];
#pragma unroll
    for (int nt = 0; nt < 4; ++nt)
      bfv[nt] = *(const bf16x8*)&Bs[(wn * 64 + nt * 16 + colL) * 32 + quad * 8];
#pragma unroll
    for (int mt = 0; mt < 4; ++mt)
#pragma unroll
      for (int nt = 0; nt < 4; ++nt)
        acc[mt][nt] =
            __builtin_amdgcn_mfma_f32_16x16x32_bf16(af[mt], bfv[nt], acc[mt][nt], 0, 0, 0);
  }

#pragma unroll
  for (int nt = 0; nt < 4; ++nt) {
    const int c = c0 + wn * 64 + nt * 16 + colL;
    float bias = 0.f;
    if (bq) bias = (c < KOFF) ? bq[c] : (c < VOFF ? bk2[c - KOFF] : bv2[c - VOFF]);
#pragma unroll
    for (int mt = 0; mt < 4; ++mt) {
#pragma unroll
      for (int i = 0; i < 4; ++i) {
        const int r = r0 + wm * 64 + mt * 16 + quad * 4 + i;
        const float v = acc[mt][nt][i] + bias;
        if (BF16OUT)
          ((bf16*)Cout)[(size_t)r * N + c] = __float2bfloat16(v);
        else
          ((float*)Cout)[(size_t)r * N + c] = v;
      }
    }
  }
}

// ---------------------------------------------------------------------------
// Causal GQA flash attention v12: v11 + 4 blocks/CU (40KB LDS).
// V triple-buffer @distance 2 -> DOUBLE buffer @distance 1 (kp/vp are
// L2-resident: each XCD's bk-slice = 4MB = its L2; one-iter latency budget
// ~600ns >> L2 hit). LDS 24+16 = 40KB -> exactly 4 blocks/CU (was 3), +33%
// resident waves on a latency-bound kernel.
// vmcnt ledger (V issued BEFORE K each iter): steady iter issues V(tt+1),
// K(tt+3); end-of-iter vmcnt(2) leaves only this iter's K outstanding and
// drains K(tt+2) (prev iter) + V(tt+1) — exactly next iter's reads. Tail:
// vmcnt(0) when no K staged. FIFO-walked for nkv=1,4,steady.
// Everything else = v11: 16-row q-tiles, 1024 blocks, LPT descending order,
// bk=id&7 XCD-local kv streams, in-register Q RoPE, PV as single K=32 MFMA
// per ht (pack_kv r4 key permutation), fixed-max softmax (exact).
// ---------------------------------------------------------------------------
#define FA_SCL2 (0.08838834764831845f * 1.4426950408889634f)  // scale * log2(e)
#define FA_M2 16.0f                                           // fixed max (exp2 domain)

__global__ __launch_bounds__(256, 4) void flash_mfma8(
    const bf16* __restrict__ qkv, const bf16* __restrict__ kp,
    const bf16* __restrict__ vp, bf16* __restrict__ ao,
    const float2* __restrict__ tab) {
  __shared__ __align__(16) bf16 KS[3][4096];   // 3 x 8KB
  __shared__ __align__(16) bf16 VS[2][4096];   // 2 x 8KB

  const int id = blockIdx.x;
  const int bk = id & 7;                   // b*KVH + kvh  (== XCD id under %8 rr)
  const int u = id >> 3;                   // 0..127
  const int jq = 127 - u;                  // descending work order (LPT)
  const int b = bk >> 2, kvh = bk & 3;
  const int w = threadIdx.x >> 6;          // wave = q-head within group
  const int h = (kvh << 2) | w;
  const int lane = threadIdx.x & 63;
  const int colL = lane & 15, quad = lane >> 4;
  const int myq0 = jq * 16;                // 16 q-rows per block
  const int nkv = (jq >> 1) + 1;           // 32-row kv tiles covering causal range

  const bf16* kpt = kp + ((size_t)(bk * 64)) * 4096 + (w * 2) * 512 + lane * 8;
  const bf16* vpt = vp + ((size_t)(bk * 64)) * 4096 + (w * 2) * 512 + lane * 8;

  auto stageK = [&](int tile, int slot) {
    const bf16* s = kpt + (size_t)tile * 4096;
    bf16* d = &KS[slot][(w * 2) * 512];    // wave-uniform base; HW adds lane*16B
    gload_lds16(s, d);
    gload_lds16(s + 512, d + 512);
  };
  auto stageV = [&](int tile, int slot) {
    const bf16* s = vpt + (size_t)tile * 4096;
    bf16* d = &VS[slot][(w * 2) * 512];
    gload_lds16(s, d);
    gload_lds16(s + 512, d + 512);
  };

  // Q fragments (B-operand of K·Q^T), RoPE'd in registers.
  bf16x8 qf[4];
  {
    const bf16* qg = qkv + (size_t)(b * T_ + myq0) * NQKV + h * HD_;
    bf16x8 rq[4];
#pragma unroll
    for (int c = 0; c < 4; ++c)
      rq[c] = *(const bf16x8*)(qg + (size_t)colL * NQKV + c * 32 + quad * 8);
    const float2* tp = tab + (myq0 + colL) * 64 + quad * 8;
    float2 cs0[8], cs1[8];
#pragma unroll
    for (int jj = 0; jj < 8; ++jj) { cs0[jj] = tp[jj]; cs1[jj] = tp[32 + jj]; }
#pragma unroll
    for (int c = 0; c < 4; ++c) {
#pragma unroll
      for (int jj = 0; jj < 8; ++jj) {
        const float2 cs = (c & 1) ? cs1[jj] : cs0[jj];
        const float a = bfh2f(rq[c][jj]), p = bfh2f(rq[c ^ 2][jj]);
        qf[c][jj] = f2bf((c & 2) ? (a * cs.x + p * cs.y)
                                 : (a * cs.x - p * cs.y));
      }
    }
  }

  const f32x4 zero = {0.f, 0.f, 0.f, 0.f};
  auto qk = [&](const bf16* Kb, f32x4 (&s_)[2]) {
    s_[0] = zero; s_[1] = zero;
#pragma unroll
    for (int c = 0; c < 4; ++c) {
      bf16x8 kf0 = *(const bf16x8*)(Kb + c * 512 + lane * 8);
      bf16x8 kf1 = *(const bf16x8*)(Kb + (4 + c) * 512 + lane * 8);
      s_[0] = mfma32k(kf0, qf[c], s_[0]);
      s_[1] = mfma32k(kf1, qf[c], s_[1]);
    }
  };

  f32x4 o[8];
#pragma unroll
  for (int ht = 0; ht < 8; ++ht) o[ht] = zero;
  float l_ = 0.f;

  // prologue: K tiles 0..2, V tile 0; full drain; QK(0)
  stageK(0, 0);
  if (nkv > 1) stageK(1, 1);
  if (nkv > 2) stageK(2, 2);
  stageV(0, 0);
  asm volatile("s_waitcnt vmcnt(0)\n\ts_barrier" ::: "memory");

  f32x4 sA[2], sB[2];
  qk(KS[0], sA);

  int kStage = 0, kNext = 1;
#pragma unroll 1
  for (int tt = 0; tt < nkv; ++tt) {
    const bool sv = (tt + 1 < nkv), sk = (tt + 3 < nkv);
    if (sv) stageV(tt + 1, (tt + 1) & 1);  // V first: ledger order for vmcnt
    if (sk) stageK(tt + 3, kStage);        // overwrites K(tt) slot: dead since iter tt-1

    // QK(t+1) first: MFMA pipe busy while VALU does softmax(t)
    if (sv) qk(KS[kNext], sB);

    // softmax on sA (tile tt); key-in-frame = quad*8 + kt*4 + i (r4 mapping)
    bf16x4 pf[2];
    if (tt == nkv - 1) {
      const int qg = ((jq & 1) << 4) | colL;   // q offset within 32-row kv frame
#pragma unroll
      for (int kt = 0; kt < 2; ++kt) {
        const int kb = quad * 8 + kt * 4;
        float pv[4];
#pragma unroll
        for (int i = 0; i < 4; ++i) {
          float e = fexp2(fmaf(sA[kt][i], FA_SCL2, -FA_M2));
          pv[i] = (kb + i <= qg) ? e : 0.f;
        }
        l_ += (pv[0] + pv[1]) + (pv[2] + pv[3]);
        pf[kt] = (bf16x4){f2bf(pv[0]), f2bf(pv[1]), f2bf(pv[2]), f2bf(pv[3])};
      }
    } else {
#pragma unroll
      for (int kt = 0; kt < 2; ++kt) {
        float pv[4];
#pragma unroll
        for (int i = 0; i < 4; ++i)
          pv[i] = fexp2(fmaf(sA[kt][i], FA_SCL2, -FA_M2));
        l_ += (pv[0] + pv[1]) + (pv[2] + pv[3]);
        pf[kt] = (bf16x4){f2bf(pv[0]), f2bf(pv[1]), f2bf(pv[2]), f2bf(pv[3])};
      }
    }

    // PV(tt): O^T += V^T · P^T — single K=32 MFMA per ht
    {
      const bf16* Vb = VS[tt & 1];
      const bf16x8 pcat = __builtin_shufflevector(pf[0], pf[1], 0, 1, 2, 3, 4, 5, 6, 7);
#pragma unroll
      for (int ht = 0; ht < 8; ++ht) {
        bf16x8 vf8 = *(const bf16x8*)(Vb + ht * 512 + lane * 8);
        o[ht] = mfma32k(vf8, pcat, o[ht]);
      }
    }

    // counted wait: keep only THIS iter's K prefetch outstanding
    if (sk) asm volatile("s_waitcnt vmcnt(2)\n\ts_barrier" ::: "memory");
    else    asm volatile("s_waitcnt vmcnt(0)\n\ts_barrier" ::: "memory");

    sA[0] = sB[0]; sA[1] = sB[1];
    kStage = (kStage == 2) ? 0 : kStage + 1;
    kNext  = (kNext == 2) ? 0 : kNext + 1;
  }

  // epilogue: reduce l over key-quads, scale, direct store
  {
    float lv = l_;
    lv += __shfl_xor(lv, 16);
    lv += __shfl_xor(lv, 32);
    const float rl = 1.f / lv;
    const size_t rbase = (size_t)(b * T_ + myq0 + colL) * (H_ * HD_) + h * HD_;
#pragma unroll
    for (int ht = 0; ht < 8; ++ht) {
      bf16x4 ov;
#pragma unroll
      for (int i = 0; i < 4; ++i) ov[i] = f2bf(o[ht][i] * rl);
      *(bf16x4*)(ao + rbase + ht * 16 + quad * 4) = ov;
    }
  }
}

// ---------------------------------------------------------------------------
extern "C" void kernel_launch(void* const* d_in, const int* in_sizes, int n_in,
                              void* d_out, int out_size, void* d_ws, size_t ws_size,
                              hipStream_t stream) {
  (void)in_sizes; (void)n_in; (void)out_size; (void)ws_size;
  const float* x  = (const float*)d_in[0];
  const float* wq = (const float*)d_in[1];
  const float* bq = (const float*)d_in[2];
  const float* wk = (const float*)d_in[3];
  const float* bk = (const float*)d_in[4];
  const float* wv = (const float*)d_in[5];
  const float* bv = (const float*)d_in[6];
  const float* wo = (const float*)d_in[7];
  float* out = (float*)d_out;

  char* ws = (char*)d_ws;
  bf16* xb    = (bf16*)ws;                 // 16 MiB; reused as ao after QKV gemm
  bf16* wqkvT = (bf16*)(ws + (16u << 20)); // 12 MiB [3072][2048]
  bf16* woT   = (bf16*)(ws + (28u << 20)); //  8 MiB [2048][2048]
  bf16* qkv   = (bf16*)(ws + (36u << 20)); // 24 MiB [4096][3072] (pre-rope Q/K)
  bf16* kp    = (bf16*)(ws + (60u << 20)); //  8 MiB fragment-major roped K'
  bf16* vp    = (bf16*)(ws + (68u << 20)); //  8 MiB fragment-major V'
  float2* tab = (float2*)(ws + (76u << 20)); // 1 MiB RoPE cos/sin [2048][64]

  // 1: all independent prep (cast, weight transposes, rope table)
  prep_kernel<<<dim3(18944), dim3(256), 0, stream>>>(
      x, xb, wq, wk, wv, wqkvT, wo, woT, tab);

  // 2: fused QKV projection (m97 structure, proven)
  gemm_mfma<true><<<dim3(NQKV / 128, MROWS / 128), dim3(256), 0, stream>>>(
      xb, wqkvT, qkv, bq, bk, bv, MROWS, NQKV, C_);

  // 3: K rope+pack, V pack (one launch)
  pack_kv<<<dim3(1024), dim3(256), 0, stream>>>(qkv, kp, vp, tab);

  // 4: flash attention (Q roped in registers, 4 blocks/CU)
  bf16* ao = xb;
  flash_mfma8<<<dim3(1024), dim3(256), 0, stream>>>(qkv, kp, vp, ao, tab);

  // 5: output projection (m97 structure, proven)
  gemm_mfma<false><<<dim3(C_ / 128, MROWS / 128), dim3(256), 0, stream>>>(
      ao, woT, out, nullptr, nullptr, nullptr, MROWS, C_, KOFF);
}

// Round 7
// 289.607 us; speedup vs baseline: 1.0757x; 1.0495x over previous
//
#include <hip/hip_runtime.h>
#include <hip/hip_bf16.h>
#include <math.h>

#define B_ 2
#define T_ 2048
#define C_ 2048
#define H_ 16
#define KVH_ 4
#define HD_ 128
#define G_ (H_ / KVH_)
#define MROWS (B_ * T_)                    // 4096
#define NQKV (H_ * HD_ + 2 * KVH_ * HD_)   // 3072
#define KOFF (H_ * HD_)                    // 2048
#define VOFF (H_ * HD_ + KVH_ * HD_)       // 2560
#define L2T (13.287712379549449f / 64.0f)  // log2(10000)/64

typedef __hip_bfloat16 bf16;
typedef short bf16x8 __attribute__((ext_vector_type(8)));   // 8 bf16 = 4 VGPR
typedef short bf16x4 __attribute__((ext_vector_type(4)));   // 4 bf16 = 2 VGPR
typedef float f32x4 __attribute__((ext_vector_type(4)));

__device__ __forceinline__ void gload_lds16(const void* g, void* l) {
  __builtin_amdgcn_global_load_lds(
      (const __attribute__((address_space(1))) unsigned int*)g,
      (__attribute__((address_space(3))) unsigned int*)l, 16, 0, 0);
}

static __device__ __forceinline__ f32x4 mfma32k(bf16x8 a, bf16x8 b, f32x4 c) {
  return __builtin_amdgcn_mfma_f32_16x16x32_bf16(a, b, c, 0, 0, 0);
}

// fast RNE f32->bf16 (no NaN handling; inputs are finite)
static __device__ __forceinline__ short f2bf(float x) {
  unsigned u = __builtin_bit_cast(unsigned, x);
  u += 0x7FFFu + ((u >> 16) & 1u);
  return (short)(u >> 16);
}

// bf16 (raw short) -> f32
static __device__ __forceinline__ float bfh2f(short h) {
  unsigned u = ((unsigned)(unsigned short)h) << 16;
  return __builtin_bit_cast(float, u);
}

static __device__ __forceinline__ float fexp2(float x) {
#if __has_builtin(__builtin_amdgcn_exp2f)
  return __builtin_amdgcn_exp2f(x);
#else
  return exp2f(x);
#endif
}

// ---------------------------------------------------------------------------
// Fused prep: [0,8192)   cast x fp32->bf16
//             [8192,14336)  wq|wk|wv transpose-cast -> wqkvT [3072][2048]
//             [14336,18432) wo transpose-cast -> woT [2048][2048]
//             [18432,18944) RoPE cos/sin table [2048][64] float2
// ---------------------------------------------------------------------------
__global__ __launch_bounds__(256) void prep_kernel(
    const float* __restrict__ x, bf16* __restrict__ xb,
    const float* __restrict__ wq, const float* __restrict__ wk,
    const float* __restrict__ wv, bf16* __restrict__ wqkvT,
    const float* __restrict__ wo, bf16* __restrict__ woT,
    float2* __restrict__ tab) {
  __shared__ float t[32][33];
  int bid = blockIdx.x;
  if (bid < 8192) {                        // ---- cast x
    const int i = (bid * 256 + threadIdx.x) * 4;
    float4 v = *(const float4*)(x + i);
    xb[i + 0] = __float2bfloat16(v.x);
    xb[i + 1] = __float2bfloat16(v.y);
    xb[i + 2] = __float2bfloat16(v.z);
    xb[i + 3] = __float2bfloat16(v.w);
    return;
  }
  bid -= 8192;
  if (bid < 6144) {                        // ---- qkv weight transpose
    const int tx = threadIdx.x & 31, ty = threadIdx.x >> 5;
    const int c0 = (bid % 96) * 32;        // fused n-dim 0..3071
    const int r0 = (bid / 96) * 32;        // k-dim
    const float* src;
    int nn, ld;
    if (c0 < KOFF)      { src = wq; nn = c0;        ld = 2048; }
    else if (c0 < VOFF) { src = wk; nn = c0 - KOFF; ld = 512; }
    else                { src = wv; nn = c0 - VOFF; ld = 512; }
#pragma unroll
    for (int it = 0; it < 4; ++it)
      t[ty + 8 * it][tx] = src[(size_t)(r0 + ty + 8 * it) * ld + nn + tx];
    __syncthreads();
#pragma unroll
    for (int it = 0; it < 4; ++it)
      wqkvT[(size_t)(c0 + ty + 8 * it) * 2048 + r0 + tx] =
          __float2bfloat16(t[tx][ty + 8 * it]);
    return;
  }
  bid -= 6144;
  if (bid < 4096) {                        // ---- wo transpose
    const int tx = threadIdx.x & 31, ty = threadIdx.x >> 5;
    const int c0 = (bid & 63) * 32;
    const int r0 = (bid >> 6) * 32;
#pragma unroll
    for (int it = 0; it < 4; ++it)
      t[ty + 8 * it][tx] = wo[(size_t)(r0 + ty + 8 * it) * 2048 + c0 + tx];
    __syncthreads();
#pragma unroll
    for (int it = 0; it < 4; ++it)
      woT[(size_t)(c0 + ty + 8 * it) * 2048 + r0 + tx] =
          __float2bfloat16(t[tx][ty + 8 * it]);
    return;
  }
  bid -= 4096;
  {                                        // ---- RoPE table
    const int idx = bid * 256 + threadIdx.x;   // [0, 131072)
    const int tt = idx >> 6, i = idx & 63;
    const float invf = fexp2(-(float)i * L2T);
    float s, c;
    __sincosf((float)tt * invf, &s, &c);
    tab[idx] = make_float2(c, s);
  }
}

// ---------------------------------------------------------------------------
// Fused pack (PV-mfma32 layout, r4):
// K chunk ((bk*64 + tile)*8 + kt*4 + c)*512 + L*8 holds (RoPE'd)
//   K[b, t = tile*32 + ((L>>2)&3)*8 + kt*4 + (L&3), kvh][c*32 + (L>>4)*8 ..+8]
//   => QK output sA[kt] row m=quad*4+i corresponds to key quad*8 + kt*4 + i.
// V chunk ((bk*64 + tile)*8 + ht)*512 + L*8 holds
//   V[b, t = tile*32 + (L>>4)*8 + j, kvh][ht*16 + (L&15)]  (j = 0..7)
//   => exact A-operand of mfma_16x16x32 for PV (k = quad*8 + j).
// ---------------------------------------------------------------------------
__global__ __launch_bounds__(256) void pack_kv(const bf16* __restrict__ qkv,
                                               bf16* __restrict__ kp,
                                               bf16* __restrict__ vp,
                                               const float2* __restrict__ tab) {
  const int pid = blockIdx.x;
  if (pid < 512) {                         // ---- K with RoPE
    const int tile = pid & 63;
    const int bk = pid >> 6;               // b*KVH + kvh
    const int b = bk >> 2, kvh = bk & 3;
#pragma unroll
    for (int u = 0; u < 2; ++u) {
      const int t = threadIdx.x + u * 256; // chunk id 0..511
      const int kc = t >> 6, L = t & 63;
      const int trow = tile * 32 + ((L >> 2) & 3) * 8 + (kc >> 2) * 4 + (L & 3);
      const bf16* src = qkv + (size_t)(b * T_ + trow) * NQKV +
                        KOFF + kvh * HD_ + (kc & 3) * 32 + (L >> 4) * 8;
      bf16x8 vs = *(const bf16x8*)src;
      bf16x8 vpair = *(const bf16x8*)(src + (((kc & 2) == 0) ? 64 : -64));
      const float2* tp = tab + trow * 64 + (kc & 1) * 32 + (L >> 4) * 8;
      bf16x8 outv;
#pragma unroll
      for (int jj = 0; jj < 8; ++jj) {
        const float2 cs = tp[jj];
        const float a = bfh2f(vs[jj]), p = bfh2f(vpair[jj]);
        outv[jj] = f2bf(((kc & 2) == 0) ? (a * cs.x - p * cs.y)
                                        : (a * cs.x + p * cs.y));
      }
      *(bf16x8*)(kp + ((size_t)(bk * 64 + tile) * 8 + kc) * 512 + L * 8) = outv;
    }
    return;
  }
  {                                        // ---- V pack (no rope)
    const int pid2 = pid - 512;
    const int tile = pid2 & 63;
    const int bk = pid2 >> 6;
    const int b = bk >> 2, kvh = bk & 3;
#pragma unroll
    for (int u = 0; u < 2; ++u) {
      const int t = threadIdx.x + u * 256;
      const int ht = t >> 6, L = t & 63;
      const int colL = L & 15, quad = L >> 4;
      const bf16* base = qkv + (size_t)(b * T_ + tile * 32 + quad * 8) * NQKV +
                         VOFF + kvh * HD_ + ht * 16 + colL;
      bf16x8 v;
#pragma unroll
      for (int jj = 0; jj < 8; ++jj)
        v[jj] = *(const short*)(base + (size_t)jj * NQKV);
      *(bf16x8*)(vp + ((size_t)(bk * 64 + tile) * 8 + ht) * 512 + L * 8) = v;
    }
  }
}

// ---------------------------------------------------------------------------
// bf16 MFMA GEMM, m97 loop structure with BK=64 + XOR swizzle (r7).
// Same 128x128 tile / 4 waves / 2-barrier-per-tile schedule as m97, but each
// K-tile covers 64 k (halves barrier drains and loop overhead vs BK=32).
// 128B LDS rows would be a 16-way bank conflict on the b128 fragment reads
// (G4), so the 16B k-slot is XOR-swizzled with row&7: read slot' =
// (ks*4+quad)^(colL&7) (fragment rows have row&7 == colL&7); write side stays
// LINEAR for global_load_lds with the same involution pre-applied to the
// global source slot ((lane&7)^(lane>>3); each gload covers an 8-row-aligned
// group so row&7 == lane>>3). Residual conflict: rows colL and colL+8 share a
// slot map but differ by 1024B (bank-identical) -> 2-way, free (m136).
// LDS 2x16KB=32KB -> still 2 blocks/CU. Staging: 16 segs x 8 rows x 128B,
// 4 gload_lds16 per wave per matrix. Verified ledger: __syncthreads drains
// vmcnt (HIP semantics) so no explicit waits needed.
// ---------------------------------------------------------------------------
template <bool BF16OUT>
__global__ __launch_bounds__(256, 2) void gemm_mfma64(
    const bf16* __restrict__ A, const bf16* __restrict__ Bt, void* __restrict__ Cout,
    const float* __restrict__ bq, const float* __restrict__ bk2,
    const float* __restrict__ bv2, int M, int N, int K) {
  __shared__ __align__(16) bf16 As[128 * 64];   // 16KB
  __shared__ __align__(16) bf16 Bs[128 * 64];   // 16KB
  const int tid = threadIdx.x;
  const int w = tid >> 6, lane = tid & 63;
  const int colL = lane & 15, quad = lane >> 4;
  const int wm = w & 1, wn = w >> 1;
  const int r0 = blockIdx.y * 128, c0 = blockIdx.x * 128;
  const int lrow = lane >> 3;                 // src row within 8-row seg
  const int lsl = ((lane & 7) ^ lrow) * 8;    // pre-swizzled src k-elems
  const int c7 = colL & 7;
  const int sq0 = (quad ^ c7) * 8;            // read slot (elems), ks=0
  const int sq1 = ((4 + quad) ^ c7) * 8;      // ks=1

  f32x4 acc[4][4];
  const f32x4 zero = {0.f, 0.f, 0.f, 0.f};
#pragma unroll
  for (int mt = 0; mt < 4; ++mt)
#pragma unroll
    for (int nt = 0; nt < 4; ++nt) acc[mt][nt] = zero;

  const bf16* pa = A + (size_t)(r0 + lrow) * K + lsl;
  const bf16* pb = Bt + (size_t)(c0 + lrow) * K + lsl;

  for (int k0 = 0; k0 < K; k0 += 64) {
    __syncthreads();                       // WAR: prev reads done (drains vmcnt too)
#pragma unroll
    for (int it = 0; it < 4; ++it) {
      const int seg = it * 4 + w;          // 16 segs x 8 rows x 128B
      gload_lds16(pa + (size_t)seg * 8 * K + k0, &As[seg * 8 * 64]);
      gload_lds16(pb + (size_t)seg * 8 * K + k0, &Bs[seg * 8 * 64]);
    }
    __syncthreads();                       // RAW: staging complete
#pragma unroll
    for (int ks = 0; ks < 2; ++ks) {
      const int sq = ks ? sq1 : sq0;
      bf16x8 af[4], bfv[4];
#pragma unroll
      for (int mt = 0; mt < 4; ++mt)
        af[mt] = *(const bf16x8*)&As[(wm * 64 + mt * 16 + colL) * 64 + sq];
#pragma unroll
      for (int nt = 0; nt < 4; ++nt)
        bfv[nt] = *(const bf16x8*)&Bs[(wn * 64 + nt * 16 + colL) * 64 + sq];
#pragma unroll
      for (int mt = 0; mt < 4; ++mt)
#pragma unroll
        for (int nt = 0; nt < 4; ++nt)
          acc[mt][nt] = mfma32k(af[mt], bfv[nt], acc[mt][nt]);
    }
  }

#pragma unroll
  for (int nt = 0; nt < 4; ++nt) {
    const int c = c0 + wn * 64 + nt * 16 + colL;
    float bias = 0.f;
    if (bq) bias = (c < KOFF) ? bq[c] : (c < VOFF ? bk2[c - KOFF] : bv2[c - VOFF]);
#pragma unroll
    for (int mt = 0; mt < 4; ++mt) {
#pragma unroll
      for (int i = 0; i < 4; ++i) {
        const int r = r0 + wm * 64 + mt * 16 + quad * 4 + i;
        const float v = acc[mt][nt][i] + bias;
        if (BF16OUT)
          ((bf16*)Cout)[(size_t)r * N + c] = __float2bfloat16(v);
        else
          ((float*)Cout)[(size_t)r * N + c] = v;
      }
    }
  }
}

// ---------------------------------------------------------------------------
// Causal GQA flash attention v13: v12 + sum-constant CU work mapping.
// r6 analysis: with 1024 blocks and capacity exactly 4/CU, ALL blocks are
// resident at t=0 (no queue) — "LPT order" did nothing. Under round-robin
// dispatch a CU hosts u in {c, c+32, c+64, c+96}; the old jq=127-u gave
// per-CU tile sums 96..158 (1.6x imbalance). New bijection makes every CU's
// sum ~130: a=u>>5, v=u&31; jq = a==0? v : a==1? 63-v : a==2? 64+v : 127-v.
// Everything else = v12: 16-row q-tiles, 4 blocks/CU (40KB LDS: K 3x8KB @
// distance 3, V 2x8KB @ distance 1 — kp/vp are L2-resident), counted
// vmcnt(2)/(0) + barrier per tile, QK(t+1) before softmax(t)/PV(t),
// in-register Q RoPE, PV as single K=32 MFMA per ht, fixed-max softmax.
// ---------------------------------------------------------------------------
#define FA_SCL2 (0.08838834764831845f * 1.4426950408889634f)  // scale * log2(e)
#define FA_M2 16.0f                                           // fixed max (exp2 domain)

__global__ __launch_bounds__(256, 4) void flash_mfma8(
    const bf16* __restrict__ qkv, const bf16* __restrict__ kp,
    const bf16* __restrict__ vp, bf16* __restrict__ ao,
    const float2* __restrict__ tab) {
  __shared__ __align__(16) bf16 KS[3][4096];   // 3 x 8KB
  __shared__ __align__(16) bf16 VS[2][4096];   // 2 x 8KB

  const int id = blockIdx.x;
  const int bk = id & 7;                   // b*KVH + kvh  (== XCD id under %8 rr)
  const int u = id >> 3;                   // 0..127
  const int av = u >> 5, vv = u & 31;      // sum-constant CU mapping
  const int jq = (av == 0) ? vv : (av == 1) ? (63 - vv)
               : (av == 2) ? (64 + vv) : (127 - vv);
  const int b = bk >> 2, kvh = bk & 3;
  const int w = threadIdx.x >> 6;          // wave = q-head within group
  const int h = (kvh << 2) | w;
  const int lane = threadIdx.x & 63;
  const int colL = lane & 15, quad = lane >> 4;
  const int myq0 = jq * 16;                // 16 q-rows per block
  const int nkv = (jq >> 1) + 1;           // 32-row kv tiles covering causal range

  const bf16* kpt = kp + ((size_t)(bk * 64)) * 4096 + (w * 2) * 512 + lane * 8;
  const bf16* vpt = vp + ((size_t)(bk * 64)) * 4096 + (w * 2) * 512 + lane * 8;

  auto stageK = [&](int tile, int slot) {
    const bf16* s = kpt + (size_t)tile * 4096;
    bf16* d = &KS[slot][(w * 2) * 512];    // wave-uniform base; HW adds lane*16B
    gload_lds16(s, d);
    gload_lds16(s + 512, d + 512);
  };
  auto stageV = [&](int tile, int slot) {
    const bf16* s = vpt + (size_t)tile * 4096;
    bf16* d = &VS[slot][(w * 2) * 512];
    gload_lds16(s, d);
    gload_lds16(s + 512, d + 512);
  };

  // Q fragments (B-operand of K·Q^T), RoPE'd in registers.
  bf16x8 qf[4];
  {
    const bf16* qg = qkv + (size_t)(b * T_ + myq0) * NQKV + h * HD_;
    bf16x8 rq[4];
#pragma unroll
    for (int c = 0; c < 4; ++c)
      rq[c] = *(const bf16x8*)(qg + (size_t)colL * NQKV + c * 32 + quad * 8);
    const float2* tp = tab + (myq0 + colL) * 64 + quad * 8;
    float2 cs0[8], cs1[8];
#pragma unroll
    for (int jj = 0; jj < 8; ++jj) { cs0[jj] = tp[jj]; cs1[jj] = tp[32 + jj]; }
#pragma unroll
    for (int c = 0; c < 4; ++c) {
#pragma unroll
      for (int jj = 0; jj < 8; ++jj) {
        const float2 cs = (c & 1) ? cs1[jj] : cs0[jj];
        const float a = bfh2f(rq[c][jj]), p = bfh2f(rq[c ^ 2][jj]);
        qf[c][jj] = f2bf((c & 2) ? (a * cs.x + p * cs.y)
                                 : (a * cs.x - p * cs.y));
      }
    }
  }

  const f32x4 zero = {0.f, 0.f, 0.f, 0.f};
  auto qk = [&](const bf16* Kb, f32x4 (&s_)[2]) {
    s_[0] = zero; s_[1] = zero;
#pragma unroll
    for (int c = 0; c < 4; ++c) {
      bf16x8 kf0 = *(const bf16x8*)(Kb + c * 512 + lane * 8);
      bf16x8 kf1 = *(const bf16x8*)(Kb + (4 + c) * 512 + lane * 8);
      s_[0] = mfma32k(kf0, qf[c], s_[0]);
      s_[1] = mfma32k(kf1, qf[c], s_[1]);
    }
  };

  f32x4 o[8];
#pragma unroll
  for (int ht = 0; ht < 8; ++ht) o[ht] = zero;
  float l_ = 0.f;

  // prologue: K tiles 0..2, V tile 0; full drain; QK(0)
  stageK(0, 0);
  if (nkv > 1) stageK(1, 1);
  if (nkv > 2) stageK(2, 2);
  stageV(0, 0);
  asm volatile("s_waitcnt vmcnt(0)\n\ts_barrier" ::: "memory");

  f32x4 sA[2], sB[2];
  qk(KS[0], sA);

  int kStage = 0, kNext = 1;
#pragma unroll 1
  for (int tt = 0; tt < nkv; ++tt) {
    const bool sv = (tt + 1 < nkv), sk = (tt + 3 < nkv);
    if (sv) stageV(tt + 1, (tt + 1) & 1);  // V first: ledger order for vmcnt
    if (sk) stageK(tt + 3, kStage);        // overwrites K(tt) slot: dead since iter tt-1

    // QK(t+1) first: MFMA pipe busy while VALU does softmax(t)
    if (sv) qk(KS[kNext], sB);

    // softmax on sA (tile tt); key-in-frame = quad*8 + kt*4 + i (r4 mapping)
    bf16x4 pf[2];
    if (tt == nkv - 1) {
      const int qg = ((jq & 1) << 4) | colL;   // q offset within 32-row kv frame
#pragma unroll
      for (int kt = 0; kt < 2; ++kt) {
        const int kb = quad * 8 + kt * 4;
        float pv[4];
#pragma unroll
        for (int i = 0; i < 4; ++i) {
          float e = fexp2(fmaf(sA[kt][i], FA_SCL2, -FA_M2));
          pv[i] = (kb + i <= qg) ? e : 0.f;
        }
        l_ += (pv[0] + pv[1]) + (pv[2] + pv[3]);
        pf[kt] = (bf16x4){f2bf(pv[0]), f2bf(pv[1]), f2bf(pv[2]), f2bf(pv[3])};
      }
    } else {
#pragma unroll
      for (int kt = 0; kt < 2; ++kt) {
        float pv[4];
#pragma unroll
        for (int i = 0; i < 4; ++i)
          pv[i] = fexp2(fmaf(sA[kt][i], FA_SCL2, -FA_M2));
        l_ += (pv[0] + pv[1]) + (pv[2] + pv[3]);
        pf[kt] = (bf16x4){f2bf(pv[0]), f2bf(pv[1]), f2bf(pv[2]), f2bf(pv[3])};
      }
    }

    // PV(tt): O^T += V^T · P^T — single K=32 MFMA per ht
    {
      const bf16* Vb = VS[tt & 1];
      const bf16x8 pcat = __builtin_shufflevector(pf[0], pf[1], 0, 1, 2, 3, 4, 5, 6, 7);
#pragma unroll
      for (int ht = 0; ht < 8; ++ht) {
        bf16x8 vf8 = *(const bf16x8*)(Vb + ht * 512 + lane * 8);
        o[ht] = mfma32k(vf8, pcat, o[ht]);
      }
    }

    // counted wait: keep only THIS iter's K prefetch outstanding
    if (sk) asm volatile("s_waitcnt vmcnt(2)\n\ts_barrier" ::: "memory");
    else    asm volatile("s_waitcnt vmcnt(0)\n\ts_barrier" ::: "memory");

    sA[0] = sB[0]; sA[1] = sB[1];
    kStage = (kStage == 2) ? 0 : kStage + 1;
    kNext  = (kNext == 2) ? 0 : kNext + 1;
  }

  // epilogue: reduce l over key-quads, scale, direct store
  {
    float lv = l_;
    lv += __shfl_xor(lv, 16);
    lv += __shfl_xor(lv, 32);
    const float rl = 1.f / lv;
    const size_t rbase = (size_t)(b * T_ + myq0 + colL) * (H_ * HD_) + h * HD_;
#pragma unroll
    for (int ht = 0; ht < 8; ++ht) {
      bf16x4 ov;
#pragma unroll
      for (int i = 0; i < 4; ++i) ov[i] = f2bf(o[ht][i] * rl);
      *(bf16x4*)(ao + rbase + ht * 16 + quad * 4) = ov;
    }
  }
}

// ---------------------------------------------------------------------------
extern "C" void kernel_launch(void* const* d_in, const int* in_sizes, int n_in,
                              void* d_out, int out_size, void* d_ws, size_t ws_size,
                              hipStream_t stream) {
  (void)in_sizes; (void)n_in; (void)out_size; (void)ws_size;
  const float* x  = (const float*)d_in[0];
  const float* wq = (const float*)d_in[1];
  const float* bq = (const float*)d_in[2];
  const float* wk = (const float*)d_in[3];
  const float* bk = (const float*)d_in[4];
  const float* wv = (const float*)d_in[5];
  const float* bv = (const float*)d_in[6];
  const float* wo = (const float*)d_in[7];
  float* out = (float*)d_out;

  char* ws = (char*)d_ws;
  bf16* xb    = (bf16*)ws;                 // 16 MiB; reused as ao after QKV gemm
  bf16* wqkvT = (bf16*)(ws + (16u << 20)); // 12 MiB [3072][2048]
  bf16* woT   = (bf16*)(ws + (28u << 20)); //  8 MiB [2048][2048]
  bf16* qkv   = (bf16*)(ws + (36u << 20)); // 24 MiB [4096][3072] (pre-rope Q/K)
  bf16* kp    = (bf16*)(ws + (60u << 20)); //  8 MiB fragment-major roped K'
  bf16* vp    = (bf16*)(ws + (68u << 20)); //  8 MiB fragment-major V'
  float2* tab = (float2*)(ws + (76u << 20)); // 1 MiB RoPE cos/sin [2048][64]

  // 1: all independent prep (cast, weight transposes, rope table)
  prep_kernel<<<dim3(18944), dim3(256), 0, stream>>>(
      x, xb, wq, wk, wv, wqkvT, wo, woT, tab);

  // 2: fused QKV projection (m97 structure, BK=64 + swizzle)
  gemm_mfma64<true><<<dim3(NQKV / 128, MROWS / 128), dim3(256), 0, stream>>>(
      xb, wqkvT, qkv, bq, bk, bv, MROWS, NQKV, C_);

  // 3: K rope+pack, V pack (one launch)
  pack_kv<<<dim3(1024), dim3(256), 0, stream>>>(qkv, kp, vp, tab);

  // 4: flash attention (Q roped in registers, 4 blocks/CU, balanced mapping)
  bf16* ao = xb;
  flash_mfma8<<<dim3(1024), dim3(256), 0, stream>>>(qkv, kp, vp, ao, tab);

  // 5: output projection (m97 structure, BK=64 + swizzle)
  gemm_mfma64<false><<<dim3(C_ / 128, MROWS / 128), dim3(256), 0, stream>>>(
      ao, woT, out, nullptr, nullptr, nullptr, MROWS, C_, KOFF);
}

// Round 8
// 287.016 us; speedup vs baseline: 1.0855x; 1.0090x over previous
//
#include <hip/hip_runtime.h>
#include <hip/hip_bf16.h>
#include <math.h>

#define B_ 2
#define T_ 2048
#define C_ 2048
#define H_ 16
#define KVH_ 4
#define HD_ 128
#define G_ (H_ / KVH_)
#define MROWS (B_ * T_)                    // 4096
#define NQKV (H_ * HD_ + 2 * KVH_ * HD_)   // 3072
#define KOFF (H_ * HD_)                    // 2048
#define VOFF (H_ * HD_ + KVH_ * HD_)       // 2560
#define L2T (13.287712379549449f / 64.0f)  // log2(10000)/64

typedef __hip_bfloat16 bf16;
typedef short bf16x8 __attribute__((ext_vector_type(8)));   // 8 bf16 = 4 VGPR
typedef short bf16x4 __attribute__((ext_vector_type(4)));   // 4 bf16 = 2 VGPR
typedef float f32x4 __attribute__((ext_vector_type(4)));

__device__ __forceinline__ void gload_lds16(const void* g, void* l) {
  __builtin_amdgcn_global_load_lds(
      (const __attribute__((address_space(1))) unsigned int*)g,
      (__attribute__((address_space(3))) unsigned int*)l, 16, 0, 0);
}

static __device__ __forceinline__ f32x4 mfma32k(bf16x8 a, bf16x8 b, f32x4 c) {
  return __builtin_amdgcn_mfma_f32_16x16x32_bf16(a, b, c, 0, 0, 0);
}

// fast RNE f32->bf16 (no NaN handling; inputs are finite)
static __device__ __forceinline__ short f2bf(float x) {
  unsigned u = __builtin_bit_cast(unsigned, x);
  u += 0x7FFFu + ((u >> 16) & 1u);
  return (short)(u >> 16);
}

// bf16 (raw short) -> f32
static __device__ __forceinline__ float bfh2f(short h) {
  unsigned u = ((unsigned)(unsigned short)h) << 16;
  return __builtin_bit_cast(float, u);
}

static __device__ __forceinline__ float fexp2(float x) {
#if __has_builtin(__builtin_amdgcn_exp2f)
  return __builtin_amdgcn_exp2f(x);
#else
  return exp2f(x);
#endif
}

// ---------------------------------------------------------------------------
// Fused prep: [0,8192)   cast x fp32->bf16
//             [8192,14336)  wq|wk|wv transpose-cast -> wqkvT [3072][2048]
//             [14336,18432) wo transpose-cast -> woT [2048][2048]
//             [18432,18944) RoPE cos/sin table [2048][64] float2
// ---------------------------------------------------------------------------
__global__ __launch_bounds__(256) void prep_kernel(
    const float* __restrict__ x, bf16* __restrict__ xb,
    const float* __restrict__ wq, const float* __restrict__ wk,
    const float* __restrict__ wv, bf16* __restrict__ wqkvT,
    const float* __restrict__ wo, bf16* __restrict__ woT,
    float2* __restrict__ tab) {
  __shared__ float t[32][33];
  int bid = blockIdx.x;
  if (bid < 8192) {                        // ---- cast x
    const int i = (bid * 256 + threadIdx.x) * 4;
    float4 v = *(const float4*)(x + i);
    xb[i + 0] = __float2bfloat16(v.x);
    xb[i + 1] = __float2bfloat16(v.y);
    xb[i + 2] = __float2bfloat16(v.z);
    xb[i + 3] = __float2bfloat16(v.w);
    return;
  }
  bid -= 8192;
  if (bid < 6144) {                        // ---- qkv weight transpose
    const int tx = threadIdx.x & 31, ty = threadIdx.x >> 5;
    const int c0 = (bid % 96) * 32;        // fused n-dim 0..3071
    const int r0 = (bid / 96) * 32;        // k-dim
    const float* src;
    int nn, ld;
    if (c0 < KOFF)      { src = wq; nn = c0;        ld = 2048; }
    else if (c0 < VOFF) { src = wk; nn = c0 - KOFF; ld = 512; }
    else                { src = wv; nn = c0 - VOFF; ld = 512; }
#pragma unroll
    for (int it = 0; it < 4; ++it)
      t[ty + 8 * it][tx] = src[(size_t)(r0 + ty + 8 * it) * ld + nn + tx];
    __syncthreads();
#pragma unroll
    for (int it = 0; it < 4; ++it)
      wqkvT[(size_t)(c0 + ty + 8 * it) * 2048 + r0 + tx] =
          __float2bfloat16(t[tx][ty + 8 * it]);
    return;
  }
  bid -= 6144;
  if (bid < 4096) {                        // ---- wo transpose
    const int tx = threadIdx.x & 31, ty = threadIdx.x >> 5;
    const int c0 = (bid & 63) * 32;
    const int r0 = (bid >> 6) * 32;
#pragma unroll
    for (int it = 0; it < 4; ++it)
      t[ty + 8 * it][tx] = wo[(size_t)(r0 + ty + 8 * it) * 2048 + c0 + tx];
    __syncthreads();
#pragma unroll
    for (int it = 0; it < 4; ++it)
      woT[(size_t)(c0 + ty + 8 * it) * 2048 + r0 + tx] =
          __float2bfloat16(t[tx][ty + 8 * it]);
    return;
  }
  bid -= 4096;
  {                                        // ---- RoPE table
    const int idx = bid * 256 + threadIdx.x;   // [0, 131072)
    const int tt = idx >> 6, i = idx & 63;
    const float invf = fexp2(-(float)i * L2T);
    float s, c;
    __sincosf((float)tt * invf, &s, &c);
    tab[idx] = make_float2(c, s);
  }
}

// ---------------------------------------------------------------------------
// bf16 MFMA GEMM, m97 loop structure with BK=64 + XOR swizzle (r7), plus
// FUSED K/V rope+pack epilogue (r8) for the QKV projection.
// Main loop identical to r7 (verified): 128x128 tile, 4 waves, BK=64,
// 2 barriers/tile; LDS rows 128B with 16B-slot XOR swizzle row&7 on both
// sides (pre-swizzled gload source / swizzled ds_read).
// FUSE epilogue (QKV only, blocks with c0 >= KOFF): the 128x128 output tile
// is exactly one kv head x 4 kv-tiles (blocks are head-aligned). Instead of
// writing qkv rows + a separate pack_kv dispatch:
//   1) sync; dump bias-added acc as bf16 into the (dead) 32KB staging LDS as
//      T[128][128], col XOR-swizzled with (row&7)<<3 (8-aligned groups map to
//      8-aligned groups -> 16B read contiguity preserved; K-read conflict
//      16-way -> 4-way);
//   2) barrier; each thread emits 8 x 16B units in the r4-verified kp/vp
//      fragment-major layouts; K gets table-RoPE in f32 (single rounding).
// Q blocks (c0 < KOFF) write qkv rows as before (flash reads only Q cols).
// ---------------------------------------------------------------------------
template <bool BF16OUT, bool FUSE>
__global__ __launch_bounds__(256, 2) void gemm_mfma64(
    const bf16* __restrict__ A, const bf16* __restrict__ Bt, void* __restrict__ Cout,
    const float* __restrict__ bq, const float* __restrict__ bk2,
    const float* __restrict__ bv2, int M, int N, int K,
    bf16* __restrict__ kp, bf16* __restrict__ vp, const float2* __restrict__ tab) {
  __shared__ __align__(16) short SH[2 * 128 * 64];  // As | Bs; FUSE: C-tile 128x128
  short* As = SH;
  short* Bs = SH + 128 * 64;
  const int tid = threadIdx.x;
  const int w = tid >> 6, lane = tid & 63;
  const int colL = lane & 15, quad = lane >> 4;
  const int wm = w & 1, wn = w >> 1;
  const int r0 = blockIdx.y * 128, c0 = blockIdx.x * 128;
  const int lrow = lane >> 3;                 // src row within 8-row seg
  const int lsl = ((lane & 7) ^ lrow) * 8;    // pre-swizzled src k-elems
  const int c7 = colL & 7;
  const int sq0 = (quad ^ c7) * 8;            // read slot (elems), ks=0
  const int sq1 = ((4 + quad) ^ c7) * 8;      // ks=1

  f32x4 acc[4][4];
  const f32x4 zero = {0.f, 0.f, 0.f, 0.f};
#pragma unroll
  for (int mt = 0; mt < 4; ++mt)
#pragma unroll
    for (int nt = 0; nt < 4; ++nt) acc[mt][nt] = zero;

  const bf16* pa = A + (size_t)(r0 + lrow) * K + lsl;
  const bf16* pb = Bt + (size_t)(c0 + lrow) * K + lsl;

  for (int k0 = 0; k0 < K; k0 += 64) {
    __syncthreads();                       // WAR: prev reads done (drains vmcnt too)
#pragma unroll
    for (int it = 0; it < 4; ++it) {
      const int seg = it * 4 + w;          // 16 segs x 8 rows x 128B
      gload_lds16(pa + (size_t)seg * 8 * K + k0, &As[seg * 8 * 64]);
      gload_lds16(pb + (size_t)seg * 8 * K + k0, &Bs[seg * 8 * 64]);
    }
    __syncthreads();                       // RAW: staging complete
#pragma unroll
    for (int ks = 0; ks < 2; ++ks) {
      const int sq = ks ? sq1 : sq0;
      bf16x8 af[4], bfv[4];
#pragma unroll
      for (int mt = 0; mt < 4; ++mt)
        af[mt] = *(const bf16x8*)&As[(wm * 64 + mt * 16 + colL) * 64 + sq];
#pragma unroll
      for (int nt = 0; nt < 4; ++nt)
        bfv[nt] = *(const bf16x8*)&Bs[(wn * 64 + nt * 16 + colL) * 64 + sq];
#pragma unroll
      for (int mt = 0; mt < 4; ++mt)
#pragma unroll
        for (int nt = 0; nt < 4; ++nt)
          acc[mt][nt] = mfma32k(af[mt], bfv[nt], acc[mt][nt]);
    }
  }

  if (!FUSE || c0 < KOFF) {
    // ---- plain epilogue: (bias +) store to Cout
#pragma unroll
    for (int nt = 0; nt < 4; ++nt) {
      const int c = c0 + wn * 64 + nt * 16 + colL;
      float bias = 0.f;
      if (bq) bias = (c < KOFF) ? bq[c] : (c < VOFF ? bk2[c - KOFF] : bv2[c - VOFF]);
#pragma unroll
      for (int mt = 0; mt < 4; ++mt) {
#pragma unroll
        for (int i = 0; i < 4; ++i) {
          const int r = r0 + wm * 64 + mt * 16 + quad * 4 + i;
          const float v = acc[mt][nt][i] + bias;
          if (BF16OUT)
            ((bf16*)Cout)[(size_t)r * N + c] = __float2bfloat16(v);
          else
            ((float*)Cout)[(size_t)r * N + c] = v;
        }
      }
    }
  } else {
    // ---- fused K/V rope+pack epilogue
    __syncthreads();                       // all As/Bs fragment reads complete
    const bool isK = (c0 < VOFF);
#pragma unroll
    for (int nt = 0; nt < 4; ++nt) {
      const int c = c0 + wn * 64 + nt * 16 + colL;
      const float bias = isK ? bk2[c - KOFF] : bv2[c - VOFF];
      const int col = wn * 64 + nt * 16 + colL;
#pragma unroll
      for (int mt = 0; mt < 4; ++mt) {
#pragma unroll
        for (int i = 0; i < 4; ++i) {
          const int row = wm * 64 + mt * 16 + quad * 4 + i;
          SH[row * 128 + (col ^ ((row & 7) << 3))] = f2bf(acc[mt][nt][i] + bias);
        }
      }
    }
    __syncthreads();
    const int b = r0 >> 11;                         // batch
    const int tbase = (r0 & 2047) >> 5;             // first 32-row kv tile
    const int kvh = (c0 - (isK ? KOFF : VOFF)) >> 7;
    const int bkq = b * 4 + kvh;
    if (isK) {
#pragma unroll
      for (int s = 0; s < 8; ++s) {
        const int unit = s * 256 + tid;             // 2048 16B-units
        const int L = unit & 63, kc = (unit >> 6) & 7, tile = unit >> 9;
        const int trow = tile * 32 + ((L >> 2) & 3) * 8 + ((kc >> 2) << 2) + (L & 3);
        const int d = (kc & 3) * 32 + ((L >> 4) << 3);
        const int sx = (trow & 7) << 3;
        bf16x8 lo = *(const bf16x8*)&SH[trow * 128 + (d ^ sx)];
        bf16x8 hi = *(const bf16x8*)&SH[trow * 128 + ((d ^ 64) ^ sx)];
        const int t_abs = (r0 + trow) & (T_ - 1);
        const float2* tp = tab + t_abs * 64 + (d & 63);
        bf16x8 outv;
#pragma unroll
        for (int j = 0; j < 8; ++j) {
          const float2 cs = tp[j];
          const float a = bfh2f(lo[j]), p = bfh2f(hi[j]);
          outv[j] = f2bf((d < 64) ? (a * cs.x - p * cs.y) : (a * cs.x + p * cs.y));
        }
        *(bf16x8*)(kp + ((size_t)((bkq * 64 + tbase + tile) * 8 + kc)) * 512 + L * 8) = outv;
      }
    } else {
#pragma unroll
      for (int s = 0; s < 8; ++s) {
        const int unit = s * 256 + tid;
        const int L = unit & 63, ht = (unit >> 6) & 7, tile = unit >> 9;
        const int rowb = tile * 32 + ((L >> 4) << 3);
        const int colv = ht * 16 + (L & 15);
        bf16x8 v;
#pragma unroll
        for (int j = 0; j < 8; ++j)
          v[j] = SH[(rowb + j) * 128 + (colv ^ (((rowb + j) & 7) << 3))];
        *(bf16x8*)(vp + ((size_t)((bkq * 64 + tbase + tile) * 8 + ht)) * 512 + L * 8) = v;
      }
    }
  }
}

// ---------------------------------------------------------------------------
// Causal GQA flash attention v12 (r6 config, measured best 73.4us):
// 16-row q-tiles, 1024 blocks, jq = 127-u descending order, 4 blocks/CU
// (40KB LDS: K 3x8KB @ distance 3, V 2x8KB @ distance 1 — kp/vp L2-resident),
// counted vmcnt(2)/(0) + barrier per tile, QK(t+1) before softmax(t)/PV(t),
// in-register Q RoPE from the prep table, PV as single K=32 MFMA per ht
// (pack r4 key permutation), fixed-max softmax (exact).
// r7's sum-constant CU mapping REVERTED: it regressed ~2us (dispatch->CU
// striping assumption falsified; occupancy unchanged).
// ---------------------------------------------------------------------------
#define FA_SCL2 (0.08838834764831845f * 1.4426950408889634f)  // scale * log2(e)
#define FA_M2 16.0f                                           // fixed max (exp2 domain)

__global__ __launch_bounds__(256, 4) void flash_mfma8(
    const bf16* __restrict__ qkv, const bf16* __restrict__ kp,
    const bf16* __restrict__ vp, bf16* __restrict__ ao,
    const float2* __restrict__ tab) {
  __shared__ __align__(16) bf16 KS[3][4096];   // 3 x 8KB
  __shared__ __align__(16) bf16 VS[2][4096];   // 2 x 8KB

  const int id = blockIdx.x;
  const int bk = id & 7;                   // b*KVH + kvh  (== XCD id under %8 rr)
  const int u = id >> 3;                   // 0..127
  const int jq = 127 - u;                  // descending work order
  const int b = bk >> 2, kvh = bk & 3;
  const int w = threadIdx.x >> 6;          // wave = q-head within group
  const int h = (kvh << 2) | w;
  const int lane = threadIdx.x & 63;
  const int colL = lane & 15, quad = lane >> 4;
  const int myq0 = jq * 16;                // 16 q-rows per block
  const int nkv = (jq >> 1) + 1;           // 32-row kv tiles covering causal range

  const bf16* kpt = kp + ((size_t)(bk * 64)) * 4096 + (w * 2) * 512 + lane * 8;
  const bf16* vpt = vp + ((size_t)(bk * 64)) * 4096 + (w * 2) * 512 + lane * 8;

  auto stageK = [&](int tile, int slot) {
    const bf16* s = kpt + (size_t)tile * 4096;
    bf16* d = &KS[slot][(w * 2) * 512];    // wave-uniform base; HW adds lane*16B
    gload_lds16(s, d);
    gload_lds16(s + 512, d + 512);
  };
  auto stageV = [&](int tile, int slot) {
    const bf16* s = vpt + (size_t)tile * 4096;
    bf16* d = &VS[slot][(w * 2) * 512];
    gload_lds16(s, d);
    gload_lds16(s + 512, d + 512);
  };

  // Q fragments (B-operand of K·Q^T), RoPE'd in registers.
  bf16x8 qf[4];
  {
    const bf16* qg = qkv + (size_t)(b * T_ + myq0) * NQKV + h * HD_;
    bf16x8 rq[4];
#pragma unroll
    for (int c = 0; c < 4; ++c)
      rq[c] = *(const bf16x8*)(qg + (size_t)colL * NQKV + c * 32 + quad * 8);
    const float2* tp = tab + (myq0 + colL) * 64 + quad * 8;
    float2 cs0[8], cs1[8];
#pragma unroll
    for (int jj = 0; jj < 8; ++jj) { cs0[jj] = tp[jj]; cs1[jj] = tp[32 + jj]; }
#pragma unroll
    for (int c = 0; c < 4; ++c) {
#pragma unroll
      for (int jj = 0; jj < 8; ++jj) {
        const float2 cs = (c & 1) ? cs1[jj] : cs0[jj];
        const float a = bfh2f(rq[c][jj]), p = bfh2f(rq[c ^ 2][jj]);
        qf[c][jj] = f2bf((c & 2) ? (a * cs.x + p * cs.y)
                                 : (a * cs.x - p * cs.y));
      }
    }
  }

  const f32x4 zero = {0.f, 0.f, 0.f, 0.f};
  auto qk = [&](const bf16* Kb, f32x4 (&s_)[2]) {
    s_[0] = zero; s_[1] = zero;
#pragma unroll
    for (int c = 0; c < 4; ++c) {
      bf16x8 kf0 = *(const bf16x8*)(Kb + c * 512 + lane * 8);
      bf16x8 kf1 = *(const bf16x8*)(Kb + (4 + c) * 512 + lane * 8);
      s_[0] = mfma32k(kf0, qf[c], s_[0]);
      s_[1] = mfma32k(kf1, qf[c], s_[1]);
    }
  };

  f32x4 o[8];
#pragma unroll
  for (int ht = 0; ht < 8; ++ht) o[ht] = zero;
  float l_ = 0.f;

  // prologue: K tiles 0..2, V tile 0; full drain; QK(0)
  stageK(0, 0);
  if (nkv > 1) stageK(1, 1);
  if (nkv > 2) stageK(2, 2);
  stageV(0, 0);
  asm volatile("s_waitcnt vmcnt(0)\n\ts_barrier" ::: "memory");

  f32x4 sA[2], sB[2];
  qk(KS[0], sA);

  int kStage = 0, kNext = 1;
#pragma unroll 1
  for (int tt = 0; tt < nkv; ++tt) {
    const bool sv = (tt + 1 < nkv), sk = (tt + 3 < nkv);
    if (sv) stageV(tt + 1, (tt + 1) & 1);  // V first: ledger order for vmcnt
    if (sk) stageK(tt + 3, kStage);        // overwrites K(tt) slot: dead since iter tt-1

    // QK(t+1) first: MFMA pipe busy while VALU does softmax(t)
    if (sv) qk(KS[kNext], sB);

    // softmax on sA (tile tt); key-in-frame = quad*8 + kt*4 + i (r4 mapping)
    bf16x4 pf[2];
    if (tt == nkv - 1) {
      const int qg = ((jq & 1) << 4) | colL;   // q offset within 32-row kv frame
#pragma unroll
      for (int kt = 0; kt < 2; ++kt) {
        const int kb = quad * 8 + kt * 4;
        float pv[4];
#pragma unroll
        for (int i = 0; i < 4; ++i) {
          float e = fexp2(fmaf(sA[kt][i], FA_SCL2, -FA_M2));
          pv[i] = (kb + i <= qg) ? e : 0.f;
        }
        l_ += (pv[0] + pv[1]) + (pv[2] + pv[3]);
        pf[kt] = (bf16x4){f2bf(pv[0]), f2bf(pv[1]), f2bf(pv[2]), f2bf(pv[3])};
      }
    } else {
#pragma unroll
      for (int kt = 0; kt < 2; ++kt) {
        float pv[4];
#pragma unroll
        for (int i = 0; i < 4; ++i)
          pv[i] = fexp2(fmaf(sA[kt][i], FA_SCL2, -FA_M2));
        l_ += (pv[0] + pv[1]) + (pv[2] + pv[3]);
        pf[kt] = (bf16x4){f2bf(pv[0]), f2bf(pv[1]), f2bf(pv[2]), f2bf(pv[3])};
      }
    }

    // PV(tt): O^T += V^T · P^T — single K=32 MFMA per ht
    {
      const bf16* Vb = VS[tt & 1];
      const bf16x8 pcat = __builtin_shufflevector(pf[0], pf[1], 0, 1, 2, 3, 4, 5, 6, 7);
#pragma unroll
      for (int ht = 0; ht < 8; ++ht) {
        bf16x8 vf8 = *(const bf16x8*)(Vb + ht * 512 + lane * 8);
        o[ht] = mfma32k(vf8, pcat, o[ht]);
      }
    }

    // counted wait: keep only THIS iter's K prefetch outstanding
    if (sk) asm volatile("s_waitcnt vmcnt(2)\n\ts_barrier" ::: "memory");
    else    asm volatile("s_waitcnt vmcnt(0)\n\ts_barrier" ::: "memory");

    sA[0] = sB[0]; sA[1] = sB[1];
    kStage = (kStage == 2) ? 0 : kStage + 1;
    kNext  = (kNext == 2) ? 0 : kNext + 1;
  }

  // epilogue: reduce l over key-quads, scale, direct store
  {
    float lv = l_;
    lv += __shfl_xor(lv, 16);
    lv += __shfl_xor(lv, 32);
    const float rl = 1.f / lv;
    const size_t rbase = (size_t)(b * T_ + myq0 + colL) * (H_ * HD_) + h * HD_;
#pragma unroll
    for (int ht = 0; ht < 8; ++ht) {
      bf16x4 ov;
#pragma unroll
      for (int i = 0; i < 4; ++i) ov[i] = f2bf(o[ht][i] * rl);
      *(bf16x4*)(ao + rbase + ht * 16 + quad * 4) = ov;
    }
  }
}

// ---------------------------------------------------------------------------
extern "C" void kernel_launch(void* const* d_in, const int* in_sizes, int n_in,
                              void* d_out, int out_size, void* d_ws, size_t ws_size,
                              hipStream_t stream) {
  (void)in_sizes; (void)n_in; (void)out_size; (void)ws_size;
  const float* x  = (const float*)d_in[0];
  const float* wq = (const float*)d_in[1];
  const float* bq = (const float*)d_in[2];
  const float* wk = (const float*)d_in[3];
  const float* bk = (const float*)d_in[4];
  const float* wv = (const float*)d_in[5];
  const float* bv = (const float*)d_in[6];
  const float* wo = (const float*)d_in[7];
  float* out = (float*)d_out;

  char* ws = (char*)d_ws;
  bf16* xb    = (bf16*)ws;                 // 16 MiB; reused as ao after QKV gemm
  bf16* wqkvT = (bf16*)(ws + (16u << 20)); // 12 MiB [3072][2048]
  bf16* woT   = (bf16*)(ws + (28u << 20)); //  8 MiB [2048][2048]
  bf16* qkv   = (bf16*)(ws + (36u << 20)); // 24 MiB [4096][3072] (Q cols only)
  bf16* kp    = (bf16*)(ws + (60u << 20)); //  8 MiB fragment-major roped K'
  bf16* vp    = (bf16*)(ws + (68u << 20)); //  8 MiB fragment-major V'
  float2* tab = (float2*)(ws + (76u << 20)); // 1 MiB RoPE cos/sin [2048][64]

  // 1: all independent prep (cast, weight transposes, rope table)
  prep_kernel<<<dim3(18944), dim3(256), 0, stream>>>(
      x, xb, wq, wk, wv, wqkvT, wo, woT, tab);

  // 2: fused QKV projection + K rope+pack / V pack in epilogue
  gemm_mfma64<true, true><<<dim3(NQKV / 128, MROWS / 128), dim3(256), 0, stream>>>(
      xb, wqkvT, qkv, bq, bk, bv, MROWS, NQKV, C_, kp, vp, tab);

  // 3: flash attention (Q roped in registers, 4 blocks/CU)
  bf16* ao = xb;
  flash_mfma8<<<dim3(1024), dim3(256), 0, stream>>>(qkv, kp, vp, ao, tab);

  // 4: output projection (m97 structure, BK=64 + swizzle)
  gemm_mfma64<false, false><<<dim3(C_ / 128, MROWS / 128), dim3(256), 0, stream>>>(
      ao, woT, out, nullptr, nullptr, nullptr, MROWS, C_, KOFF,
      nullptr, nullptr, nullptr);
}